// Round 12
// baseline (212.057 us; speedup 1.0000x reference)
//
#include <hip/hip_runtime.h>
#include <hip/hip_bf16.h>

// Problem constants
#define BDIM 8
#define HDIM 64
#define WDIM 64
#define CDIM 192
#define CIDIM 384
#define MTOK (BDIM * HDIM * WDIM)   // 32768 tokens

using bf16 = __hip_bfloat16;
typedef __attribute__((ext_vector_type(8))) short short8;   // 8 bf16 (4 VGPRs)
typedef __attribute__((ext_vector_type(4))) float f32x4;

__device__ __forceinline__ float silu_f(float v) { return v / (1.0f + __expf(-v)); }
__device__ __forceinline__ float bf2f(short s) {
    union { unsigned u; float f; } x; x.u = ((unsigned)(unsigned short)s) << 16; return x.f;
}

// async global->LDS, 16B per lane. LDS dest must be WAVE-UNIFORM base (+lane*16);
// the GLOBAL source address is per-lane.
__device__ __forceinline__ void gload_lds16(const bf16* g, bf16* l) {
    __builtin_amdgcn_global_load_lds(
        (const __attribute__((address_space(1))) void*)g,
        (__attribute__((address_space(3))) void*)l, 16, 0, 0);
}

// ---------------------------------------------------------------------------
// REGISTER-DIRECT full-K GEMM for K=192 (G1, G4): C = A[M,192] @ B, B given
// TRANSPOSED [N,192], N = 768 = 12 n-tiles. NO LDS, NO barriers.
// mfma_16x16x32 fragments are per-lane 16B contiguous in [*,K] storage:
//   frag addr = (base + (lane&15))*192 + (ks*4 + (lane>>4))*8   (elements)
// -> direct global_load_dwordx4, 16 rows x 64B per wave instr (coalesced).
// B tile (64x192) = 2ni x 6ks frags = 48 VGPR, loaded once per block.
// A fragments streamed per ks. One 64x64 tile per block; latency hidden by
// occupancy (no LDS -> 4+ waves/SIMD). XCD-chunked tile map: xcd = bid&7 owns
// 64 consecutive m-panels x all 12 n -> A re-reads from own L2; B L2-resident.
// EPI 0: split-store c<384 -> outB (x1), else outB2 = 4*silu(v)      [G1]
// EPI 2: silu(v+bias) -> outB bf16, stride 768                        [G4]
// ---------------------------------------------------------------------------
template <int EPI>
__launch_bounds__(256, 4)
__global__ void gemm_k192_reg(const bf16* __restrict__ A, const bf16* __restrict__ BT,
                              const float* __restrict__ bias,
                              bf16* __restrict__ outB, bf16* __restrict__ outB2)
{
    const int bid = blockIdx.x;
    const int xcd = bid & 7;
    const int idx = bid >> 3;
    const int t   = xcd * 768 + idx;      // tile id 0..6143, XCD-chunked
    const int mt  = t / 12;
    const int nt  = t - mt * 12;
    const int m0  = mt * 64;
    const int n0  = nt * 64;

    const int lane = threadIdx.x & 63;
    const int wv   = threadIdx.x >> 6;
    const int wm   = wv >> 1;
    const int wn   = wv & 1;
    const int l15  = lane & 15;
    const int l4   = lane >> 4;

    // --- B fragments: resident in registers (2 ni x 6 ks x 16B = 48 VGPR) ---
    short8 bfr[2][6];
    #pragma unroll
    for (int ni = 0; ni < 2; ++ni) {
        const bf16* bp = BT + (size_t)(n0 + wn * 32 + ni * 16 + l15) * 192 + l4 * 8;
        #pragma unroll
        for (int ks = 0; ks < 6; ++ks)
            bfr[ni][ks] = *reinterpret_cast<const short8*>(bp + ks * 32);
    }

    // --- A streamed, 24 MFMA ---
    const bf16* ap0 = A + (size_t)(m0 + wm * 32 + l15) * 192 + l4 * 8;       // mi=0
    const bf16* ap1 = A + (size_t)(m0 + wm * 32 + 16 + l15) * 192 + l4 * 8;  // mi=1

    f32x4 acc[2][2] = {};
    #pragma unroll
    for (int ks = 0; ks < 6; ++ks) {
        const short8 a0 = *reinterpret_cast<const short8*>(ap0 + ks * 32);
        const short8 a1 = *reinterpret_cast<const short8*>(ap1 + ks * 32);
        acc[0][0] = __builtin_amdgcn_mfma_f32_16x16x32_bf16(a0, bfr[0][ks], acc[0][0], 0, 0, 0);
        acc[0][1] = __builtin_amdgcn_mfma_f32_16x16x32_bf16(a0, bfr[1][ks], acc[0][1], 0, 0, 0);
        acc[1][0] = __builtin_amdgcn_mfma_f32_16x16x32_bf16(a1, bfr[0][ks], acc[1][0], 0, 0, 0);
        acc[1][1] = __builtin_amdgcn_mfma_f32_16x16x32_bf16(a1, bfr[1][ks], acc[1][1], 0, 0, 0);
    }

    // --- epilogue: C/D layout col = lane&15, row = (lane>>4)*4 + j ---
    const bool isZ   = (EPI == 0) && (n0 >= CIDIM);
    bf16* dst        = (EPI == 0) ? (isZ ? outB2 : outB) : outB;
    const int stride = (EPI == 0) ? CIDIM : 768;
    const int col0   = (EPI == 0) ? (isZ ? n0 - CIDIM : n0) : n0;

    const int rowb = m0 + wm * 32 + l4 * 4;
    const int colb = col0 + wn * 32 + l15;
    #pragma unroll
    for (int mi = 0; mi < 2; ++mi) {
        #pragma unroll
        for (int ni = 0; ni < 2; ++ni) {
            const int c = colb + ni * 16;
            #pragma unroll
            for (int j = 0; j < 4; ++j) {
                const int row = rowb + mi * 16 + j;
                float v = acc[mi][ni][j];
                if constexpr (EPI == 0) {
                    if (isZ) v = 4.0f * silu_f(v);
                } else {
                    v = silu_f(v + bias[n0 + (c - col0)]);
                }
                dst[(size_t)row * stride + c] = __float2bfloat16(v);
            }
        }
    }
}

// ---------------------------------------------------------------------------
// Loop GEMM (K=384/768): BM=128, BN=64, BK=64. 4 waves 2x2; wave 64x32.
// 1D grid + XCD-bijective swizzle (y%8 == bid%8).
// EPI 1: +residF(fp32) -> outB bf16 only                              [G3]
// EPI 3: v + bias + bf2f(residB) -> outF fp32                         [G5]
// ---------------------------------------------------------------------------
template <int EPI>
__launch_bounds__(256, 4)
__global__ void gemm_mfma(const bf16* __restrict__ A, const bf16* __restrict__ BT,
                          const float* __restrict__ bias,
                          const float* __restrict__ residF,
                          const bf16* __restrict__ residB,
                          float* __restrict__ outF, bf16* __restrict__ outB,
                          int M, int N, int K, int NX)
{
    __shared__ bf16 As[128 * 64];
    __shared__ bf16 Bs[64 * 64];

    const int bid = blockIdx.x;
    const int c8  = bid & 7;
    const int kq  = bid >> 3;
    const int bx  = kq % NX;
    const int by  = (kq / NX) * 8 + c8;
    const int m0  = by * 128;
    const int n0  = bx * 64;

    const int tid  = threadIdx.x;
    const int lane = tid & 63;
    const int wv   = tid >> 6;
    const int wm   = wv >> 1;
    const int wn   = wv & 1;

    const int srow  = lane >> 3;
    const int sslot = lane & 7;

    f32x4 acc[4][2] = {};

    for (int k0 = 0; k0 < K; k0 += 64) {
        #pragma unroll
        for (int i = 0; i < 4; ++i) {
            const int rb = wv * 32 + i * 8;
            const int r  = rb + srow;
            gload_lds16(A + (size_t)(m0 + r) * K + k0 + ((sslot ^ (r & 7)) << 3),
                        &As[rb * 64]);
        }
        #pragma unroll
        for (int i = 0; i < 2; ++i) {
            const int rb = wv * 16 + i * 8;
            const int r  = rb + srow;
            gload_lds16(BT + (size_t)(n0 + r) * K + k0 + ((sslot ^ (r & 7)) << 3),
                        &Bs[rb * 64]);
        }
        __syncthreads();

        #pragma unroll
        for (int kk = 0; kk < 2; ++kk) {
            const int t = kk * 4 + (lane >> 4);
            short8 af[4], bfr[2];
            #pragma unroll
            for (int mi = 0; mi < 4; ++mi) {
                const int m = wm * 64 + mi * 16 + (lane & 15);
                af[mi] = *reinterpret_cast<const short8*>(&As[m * 64 + ((t ^ (m & 7)) << 3)]);
            }
            #pragma unroll
            for (int ni = 0; ni < 2; ++ni) {
                const int n = wn * 32 + ni * 16 + (lane & 15);
                bfr[ni] = *reinterpret_cast<const short8*>(&Bs[n * 64 + ((t ^ (n & 7)) << 3)]);
            }
            #pragma unroll
            for (int mi = 0; mi < 4; ++mi)
                #pragma unroll
                for (int ni = 0; ni < 2; ++ni)
                    acc[mi][ni] = __builtin_amdgcn_mfma_f32_16x16x32_bf16(
                        af[mi], bfr[ni], acc[mi][ni], 0, 0, 0);
        }
        __syncthreads();
    }

    const int colb = n0 + wn * 32 + (lane & 15);
    const int rowb = m0 + wm * 64 + (lane >> 4) * 4;
    #pragma unroll
    for (int mi = 0; mi < 4; ++mi) {
        #pragma unroll
        for (int ni = 0; ni < 2; ++ni) {
            const int c = colb + ni * 16;
            #pragma unroll
            for (int j = 0; j < 4; ++j) {
                const int row = rowb + mi * 16 + j;
                const size_t off = (size_t)row * N + c;
                const float v = acc[mi][ni][j];
                if constexpr (EPI == 1) {
                    outB[off] = __float2bfloat16(v + residF[off]);
                } else {
                    outF[off] = v + bias[c] + bf2f(*(const short*)&residB[off]);
                }
            }
        }
    }
}

// ---------------------------------------------------------------------------
// Depthwise 3x3 conv + bias + silu, gated. Dense streams:
// x1 [M,384] bf16, sz [M,384] bf16 (= 4*silu(z)). Item f = m*48 + cg.
// y[m,c] = silu(conv(x1)+b) * sz.  Grid: 6144 blocks x 256 thr, XCD-swizzled.
// ---------------------------------------------------------------------------
__launch_bounds__(256)
__global__ void dwconv_gate_v6(const bf16* __restrict__ x1, const bf16* __restrict__ sz,
                               const float* __restrict__ wT, const float* __restrict__ conv_b,
                               bf16* __restrict__ y)
{
    const int bid = blockIdx.x;
    const int swz = (bid & 7) * ((int)gridDim.x >> 3) + (bid >> 3);   // bijective (6144 % 8 == 0)
    const int f   = swz * 256 + threadIdx.x;
    const int m   = f / 48;
    const int cg  = f - m * 48;
    const int c0  = cg * 8;
    const int h   = (m >> 6) & 63;
    const int w   = m & 63;

    float acc[8];
    {
        const f32x4 ba = *reinterpret_cast<const f32x4*>(&conv_b[c0]);
        const f32x4 bb = *reinterpret_cast<const f32x4*>(&conv_b[c0 + 4]);
        acc[0] = ba[0]; acc[1] = ba[1]; acc[2] = ba[2]; acc[3] = ba[3];
        acc[4] = bb[0]; acc[5] = bb[1]; acc[6] = bb[2]; acc[7] = bb[3];
    }

    #pragma unroll
    for (int r = 0; r < 3; ++r) {
        const int hh = h + r - 1;
        if (hh < 0 || hh >= HDIM) continue;
        #pragma unroll
        for (int dw = 0; dw < 3; ++dw) {
            const int ww = w + dw - 1;
            if (ww < 0 || ww >= WDIM) continue;
            const int mm  = m + (r - 1) * WDIM + (dw - 1);
            const int tap = r * 3 + dw;
            const short8 t = *reinterpret_cast<const short8*>(&x1[(size_t)mm * CIDIM + c0]);
            const f32x4 wa = *reinterpret_cast<const f32x4*>(&wT[tap * CIDIM + c0]);
            const f32x4 wb = *reinterpret_cast<const f32x4*>(&wT[tap * CIDIM + c0 + 4]);
            acc[0] += bf2f(t[0]) * wa[0]; acc[1] += bf2f(t[1]) * wa[1];
            acc[2] += bf2f(t[2]) * wa[2]; acc[3] += bf2f(t[3]) * wa[3];
            acc[4] += bf2f(t[4]) * wb[0]; acc[5] += bf2f(t[5]) * wb[1];
            acc[6] += bf2f(t[6]) * wb[2]; acc[7] += bf2f(t[7]) * wb[3];
        }
    }

    const short8 g = *reinterpret_cast<const short8*>(&sz[(size_t)m * CIDIM + c0]);
    bf16 tmp[8];
    #pragma unroll
    for (int j = 0; j < 8; ++j)
        tmp[j] = __float2bfloat16(silu_f(acc[j]) * bf2f(g[j]));
    *reinterpret_cast<short8*>(&y[(size_t)m * CIDIM + c0]) =
        *reinterpret_cast<const short8*>(tmp);
}

// ---------------------------------------------------------------------------
// ALL preprocessing in ONE launch: x fp32->bf16 (4/thread) + 4 weight
// transposes to bf16 [N,K] + conv_w transpose, flat-index dispatched.
// ---------------------------------------------------------------------------
#define SZ_WIN  (192 * 768)
#define SZ_WOUT (384 * 192)
#define SZ_WM1  (192 * 768)
#define SZ_WM2  (768 * 192)
#define SZ_CW   (CIDIM * 9)
#define XCVT    (MTOK * CDIM / 4)
#define SZ_ALL  (XCVT + SZ_WIN + SZ_WOUT + SZ_WM1 + SZ_WM2 + SZ_CW)

__launch_bounds__(256)
__global__ void prep_all(const float* __restrict__ x, const float* __restrict__ Win,
                         const float* __restrict__ Wout, const float* __restrict__ Wm1,
                         const float* __restrict__ Wm2, const float* __restrict__ convw,
                         bf16* __restrict__ xb, bf16* __restrict__ WinT,
                         bf16* __restrict__ WoutT, bf16* __restrict__ Wm1T,
                         bf16* __restrict__ Wm2T, float* __restrict__ wTc)
{
    int idx = blockIdx.x * 256 + threadIdx.x;
    if (idx < XCVT) {
        const int i = idx * 4;
        const float4 v = *reinterpret_cast<const float4*>(&x[i]);
        xb[i + 0] = __float2bfloat16(v.x);
        xb[i + 1] = __float2bfloat16(v.y);
        xb[i + 2] = __float2bfloat16(v.z);
        xb[i + 3] = __float2bfloat16(v.w);
        return;
    }
    idx -= XCVT;
    if (idx < SZ_WIN) {
        const int r = idx / 768, c = idx % 768;
        WinT[(size_t)c * 192 + r] = __float2bfloat16(Win[idx]);
        return;
    }
    idx -= SZ_WIN;
    if (idx < SZ_WOUT) {
        const int r = idx / 192, c = idx % 192;
        WoutT[(size_t)c * 384 + r] = __float2bfloat16(Wout[idx]);
        return;
    }
    idx -= SZ_WOUT;
    if (idx < SZ_WM1) {
        const int r = idx / 768, c = idx % 768;
        Wm1T[(size_t)c * 192 + r] = __float2bfloat16(Wm1[idx]);
        return;
    }
    idx -= SZ_WM1;
    if (idx < SZ_WM2) {
        const int r = idx / 192, c = idx % 192;
        Wm2T[(size_t)c * 768 + r] = __float2bfloat16(Wm2[idx]);
        return;
    }
    idx -= SZ_WM2;
    if (idx < SZ_CW) {
        const int ci = idx / 9, t = idx % 9;
        wTc[t * CIDIM + ci] = convw[idx];
    }
}

// ---------------------------------------------------------------------------
extern "C" void kernel_launch(void* const* d_in, const int* in_sizes, int n_in,
                              void* d_out, int out_size, void* d_ws, size_t ws_size,
                              hipStream_t stream)
{
    const float* x      = (const float*)d_in[0];
    const float* Win    = (const float*)d_in[1];
    const float* conv_w = (const float*)d_in[2];
    const float* conv_b = (const float*)d_in[3];
    const float* Wout   = (const float*)d_in[4];
    const float* Wm1    = (const float*)d_in[5];
    const float* bm1    = (const float*)d_in[6];
    const float* Wm2    = (const float*)d_in[7];
    const float* bm2    = (const float*)d_in[8];
    float* out = (float*)d_out;

    char* ws = (char*)d_ws;
    size_t o = 0;
    bf16*  xb    = (bf16*)(ws + o); o += (size_t)MTOK * CDIM * 2;
    bf16*  WinT  = (bf16*)(ws + o); o += (size_t)768 * 192 * 2;
    bf16*  WoutT = (bf16*)(ws + o); o += (size_t)192 * 384 * 2;
    bf16*  Wm1T  = (bf16*)(ws + o); o += (size_t)768 * 192 * 2;
    bf16*  Wm2T  = (bf16*)(ws + o); o += (size_t)192 * 768 * 2;
    float* wTc   = (float*)(ws + o); o += (size_t)9 * CIDIM * 4;
    bf16*  ws_x1 = (bf16*)(ws + o); o += (size_t)MTOK * CIDIM * 2;   // dense x1 [M,384]
    bf16*  ws_sz = (bf16*)(ws + o); o += (size_t)MTOK * CIDIM * 2;   // dense 4*silu(z)
    bf16*  ws_y  = (bf16*)(ws + o); o += (size_t)MTOK * CIDIM * 2;
    bf16*  ws_ob = (bf16*)(ws + o); o += (size_t)MTOK * CDIM * 2;    // out bf16 [M,192]
    bf16*  ws_h  = ws_x1;   // GEMM4 output [M,768] reuses x1+sz region (dead by then)

    // 0) all conversions/transposes in one launch
    prep_all<<<dim3((SZ_ALL + 255) / 256), dim3(256), 0, stream>>>(
        x, Win, Wout, Wm1, Wm2, conv_w, xb, WinT, WoutT, Wm1T, Wm2T, wTc);

    // 1) xz = x @ Win  [M,768], K=192 -> split dense x1 / sz(=4*silu(z))
    //    register-direct, no LDS, no barriers
    gemm_k192_reg<0><<<dim3(512 * 12), dim3(256), 0, stream>>>(
        xb, WinT, nullptr, ws_x1, ws_sz);

    // 2) y = silu(dwconv(x1)+b) * sz -> bf16
    dwconv_gate_v6<<<dim3(MTOK * 48 / 256), dim3(256), 0, stream>>>(
        ws_x1, ws_sz, wTc, conv_b, ws_y);

    // 3) out = x + y @ Wout   [M,192], K=384 -> bf16 ob ONLY
    gemm_mfma<1><<<dim3(3 * 256), dim3(256), 0, stream>>>(
        ws_y, WoutT, nullptr, x, nullptr, nullptr, ws_ob, MTOK, CDIM, CIDIM, 3);

    // 4) h = silu(out @ Wm1 + bm1)   [M,768], K=192 -> bf16 (register-direct)
    gemm_k192_reg<2><<<dim3(512 * 12), dim3(256), 0, stream>>>(
        ws_ob, Wm1T, bm1, ws_h, nullptr);

    // 5) final = bf16(out) + h @ Wm2 + bm2   [M,192], K=768 -> fp32
    gemm_mfma<3><<<dim3(3 * 256), dim3(256), 0, stream>>>(
        ws_h, Wm2T, bm2, nullptr, ws_ob, out, nullptr, MTOK, CDIM, 768, 3);
}

// Round 13
// 137.044 us; speedup vs baseline: 1.5474x; 1.5474x over previous
//
#include <hip/hip_runtime.h>
#include <hip/hip_bf16.h>

// Problem constants
#define BDIM 8
#define HDIM 64
#define WDIM 64
#define CDIM 192
#define CIDIM 384
#define MTOK (BDIM * HDIM * WDIM)   // 32768 tokens

using bf16 = __hip_bfloat16;
typedef __attribute__((ext_vector_type(8))) short short8;   // 8 bf16 (4 VGPRs)
typedef __attribute__((ext_vector_type(4))) float f32x4;

__device__ __forceinline__ float silu_f(float v) { return v / (1.0f + __expf(-v)); }
__device__ __forceinline__ float bf2f(short s) {
    union { unsigned u; float f; } x; x.u = ((unsigned)(unsigned short)s) << 16; return x.f;
}

__device__ __forceinline__ void gload_lds16(const bf16* g, bf16* l) {
    __builtin_amdgcn_global_load_lds(
        (const __attribute__((address_space(1))) void*)g,
        (__attribute__((address_space(3))) void*)l, 16, 0, 0);
}

#define MFMA16(a, b, c) __builtin_amdgcn_mfma_f32_16x16x32_bf16(a, b, c, 0, 0, 0)

// ---------------------------------------------------------------------------
// PERSISTENT full-K GEMM for K=192 (G1): best-known R11 version.
// B staged once; A double-buffered; grid 480 = 12 n x 40 stripes.
// EPI 0: split-store c<384 -> outB (x1), else outB2 = 4*silu(v)
// ---------------------------------------------------------------------------
#define NSTRIPE 40
template <int EPI>
__launch_bounds__(256, 2)
__global__ void gemm_k192_p(const bf16* __restrict__ A, const bf16* __restrict__ BT,
                            const float* __restrict__ bias,
                            bf16* __restrict__ outB, bf16* __restrict__ outB2)
{
    __shared__ bf16 As[2][64 * 192];
    __shared__ bf16 Bs[64 * 192];

    const int bid = blockIdx.x;
    const int n   = bid / NSTRIPE;
    const int s   = bid % NSTRIPE;
    const int n0  = n * 64;

    const int tid  = threadIdx.x;
    const int lane = tid & 63;
    const int wv   = tid >> 6;
    const int wm   = wv >> 1;
    const int wn   = wv & 1;

    int soff[6];
    #pragma unroll
    for (int i = 0; i < 6; ++i) {
        const int ci   = wv * 6 + i;
        const int c    = ci * 64 + lane;
        const int row  = c / 24;
        const int slot = c - row * 24;
        const int lsl  = slot ^ (row & 7);
        soff[i] = row * 192 + lsl * 8;
    }

    #pragma unroll
    for (int i = 0; i < 6; ++i)
        gload_lds16(BT + (size_t)n0 * 192 + soff[i], &Bs[(wv * 6 + i) * 512]);
    #pragma unroll
    for (int i = 0; i < 6; ++i)
        gload_lds16(A + (size_t)(s * 64) * 192 + soff[i], &As[0][(wv * 6 + i) * 512]);
    __syncthreads();

    const int mloc[2] = { wm * 32 + (lane & 15), wm * 32 + 16 + (lane & 15) };
    const int nloc[2] = { wn * 32 + (lane & 15), wn * 32 + 16 + (lane & 15) };
    const bool isZ = (EPI == 0) && (n0 >= CIDIM);
    bf16* dst        = (EPI == 0) ? (isZ ? outB2 : outB) : outB;
    const int stride = (EPI == 0) ? CIDIM : 768;
    const int col0   = (EPI == 0) ? (isZ ? n0 - CIDIM : n0) : n0;

    int cur = 0;
    for (int mt = s; mt < 512; mt += NSTRIPE) {
        const int nmt = mt + NSTRIPE;
        if (nmt < 512) {
            const bf16* a1 = A + (size_t)(nmt * 64) * 192;
            bf16* db = As[cur ^ 1];
            #pragma unroll
            for (int i = 0; i < 6; ++i)
                gload_lds16(a1 + soff[i], &db[(wv * 6 + i) * 512]);
        }

        const bf16* la = As[cur];
        f32x4 acc[2][2] = {};
        #pragma unroll
        for (int ks = 0; ks < 6; ++ks) {
            const int t = ks * 4 + (lane >> 4);
            short8 af[2], bfr[2];
            #pragma unroll
            for (int mi = 0; mi < 2; ++mi) {
                const int m = mloc[mi];
                af[mi] = *reinterpret_cast<const short8*>(&la[m * 192 + ((t ^ (m & 7)) << 3)]);
            }
            #pragma unroll
            for (int ni = 0; ni < 2; ++ni) {
                const int nn = nloc[ni];
                bfr[ni] = *reinterpret_cast<const short8*>(&Bs[nn * 192 + ((t ^ (nn & 7)) << 3)]);
            }
            #pragma unroll
            for (int mi = 0; mi < 2; ++mi)
                #pragma unroll
                for (int ni = 0; ni < 2; ++ni)
                    acc[mi][ni] = MFMA16(af[mi], bfr[ni], acc[mi][ni]);
        }

        const int m0   = mt * 64;
        const int rowb = m0 + wm * 32 + (lane >> 4) * 4;
        const int colb = col0 + wn * 32 + (lane & 15);
        #pragma unroll
        for (int mi = 0; mi < 2; ++mi) {
            #pragma unroll
            for (int ni = 0; ni < 2; ++ni) {
                const int c = colb + ni * 16;
                #pragma unroll
                for (int j = 0; j < 4; ++j) {
                    const int row = rowb + mi * 16 + j;
                    float v = acc[mi][ni][j];
                    if constexpr (EPI == 0) {
                        if (isZ) v = 4.0f * silu_f(v);
                    } else {
                        v = silu_f(v + bias[n0 + (c - col0)]);
                    }
                    dst[(size_t)row * stride + c] = __float2bfloat16(v);
                }
            }
        }

        __syncthreads();
        cur ^= 1;
    }
}

// ---------------------------------------------------------------------------
// Loop GEMM (G3, K=384): BM=128, BN=64, BK=64. EPI 1: +residF -> bf16 out.
// ---------------------------------------------------------------------------
template <int EPI>
__launch_bounds__(256, 4)
__global__ void gemm_mfma(const bf16* __restrict__ A, const bf16* __restrict__ BT,
                          const float* __restrict__ residF, bf16* __restrict__ outB,
                          int M, int N, int K, int NX)
{
    __shared__ bf16 As[128 * 64];
    __shared__ bf16 Bs[64 * 64];

    const int bid = blockIdx.x;
    const int c8  = bid & 7;
    const int kq  = bid >> 3;
    const int bx  = kq % NX;
    const int by  = (kq / NX) * 8 + c8;
    const int m0  = by * 128;
    const int n0  = bx * 64;

    const int tid  = threadIdx.x;
    const int lane = tid & 63;
    const int wv   = tid >> 6;
    const int wm   = wv >> 1;
    const int wn   = wv & 1;

    const int srow  = lane >> 3;
    const int sslot = lane & 7;

    f32x4 acc[4][2] = {};

    for (int k0 = 0; k0 < K; k0 += 64) {
        #pragma unroll
        for (int i = 0; i < 4; ++i) {
            const int rb = wv * 32 + i * 8;
            const int r  = rb + srow;
            gload_lds16(A + (size_t)(m0 + r) * K + k0 + ((sslot ^ (r & 7)) << 3),
                        &As[rb * 64]);
        }
        #pragma unroll
        for (int i = 0; i < 2; ++i) {
            const int rb = wv * 16 + i * 8;
            const int r  = rb + srow;
            gload_lds16(BT + (size_t)(n0 + r) * K + k0 + ((sslot ^ (r & 7)) << 3),
                        &Bs[rb * 64]);
        }
        __syncthreads();

        #pragma unroll
        for (int kk = 0; kk < 2; ++kk) {
            const int t = kk * 4 + (lane >> 4);
            short8 af[4], bfr[2];
            #pragma unroll
            for (int mi = 0; mi < 4; ++mi) {
                const int m = wm * 64 + mi * 16 + (lane & 15);
                af[mi] = *reinterpret_cast<const short8*>(&As[m * 64 + ((t ^ (m & 7)) << 3)]);
            }
            #pragma unroll
            for (int ni = 0; ni < 2; ++ni) {
                const int n = wn * 32 + ni * 16 + (lane & 15);
                bfr[ni] = *reinterpret_cast<const short8*>(&Bs[n * 64 + ((t ^ (n & 7)) << 3)]);
            }
            #pragma unroll
            for (int mi = 0; mi < 4; ++mi)
                #pragma unroll
                for (int ni = 0; ni < 2; ++ni)
                    acc[mi][ni] = MFMA16(af[mi], bfr[ni], acc[mi][ni]);
        }
        __syncthreads();
    }

    const int colb = n0 + wn * 32 + (lane & 15);
    const int rowb = m0 + wm * 64 + (lane >> 4) * 4;
    #pragma unroll
    for (int mi = 0; mi < 4; ++mi) {
        #pragma unroll
        for (int ni = 0; ni < 2; ++ni) {
            const int c = colb + ni * 16;
            #pragma unroll
            for (int j = 0; j < 4; ++j) {
                const int row = rowb + mi * 16 + j;
                const size_t off = (size_t)row * N + c;
                outB[off] = __float2bfloat16(acc[mi][ni][j] + residF[off]);
            }
        }
    }
}

// ---------------------------------------------------------------------------
// FUSED MLP: final = ob + silu(ob@Wm1 + bm1)@Wm2 + bm2   (replaces G4+G5)
// Block = 64-row m-tile. LDS: ob[64x192] 24KB + h[64x768] 96KB = 120KB.
// Phase 1: wave wv computes h cols [wv*192, wv*192+192) (3 chunks x 64),
//          24 MFMA + silu per chunk, bf16 -> hs (XOR chunk-swizzle).
// ONE barrier. Phase 2: wave owns 48 final cols, K=768: 288 MFMA,
// A-frags from hs, B-frags (Wm2T) from L2; epilogue + bm2 + ob-resid (LDS).
// ---------------------------------------------------------------------------
__launch_bounds__(256, 1)
__global__ void fused_mlp(const bf16* __restrict__ ob, const bf16* __restrict__ Wm1T,
                          const bf16* __restrict__ Wm2T, const float* __restrict__ bm1,
                          const float* __restrict__ bm2, float* __restrict__ out)
{
    __shared__ bf16 obs[64 * 192];   // 24 KB
    __shared__ bf16 hs[64 * 768];    // 96 KB

    const int m0   = blockIdx.x * 64;
    const int tid  = threadIdx.x;
    const int lane = tid & 63;
    const int wv   = tid >> 6;
    const int l15  = lane & 15;
    const int l4   = lane >> 4;

    // stage ob tile (k192 swizzle: phys slot p of row holds logical p^(row&7))
    #pragma unroll
    for (int i = 0; i < 6; ++i) {
        const int ci   = wv * 6 + i;
        const int c    = ci * 64 + lane;
        const int row  = c / 24;
        const int slot = c - row * 24;
        gload_lds16(ob + (size_t)(m0 + row) * 192 + (slot ^ (row & 7)) * 8,
                    &obs[ci * 512]);
    }
    __syncthreads();

    // ---- phase 1: h chunks ----
    #pragma unroll
    for (int cc = 0; cc < 3; ++cc) {
        const int nc = wv * 3 + cc;          // 64-col chunk 0..11
        f32x4 hacc[4][4] = {};
        #pragma unroll
        for (int ks = 0; ks < 6; ++ks) {
            short8 af[4];
            #pragma unroll
            for (int mi = 0; mi < 4; ++mi) {
                const int r = mi * 16 + l15;
                af[mi] = *reinterpret_cast<const short8*>(
                    &obs[r * 192 + (((ks * 4 + l4) ^ (r & 7)) << 3)]);
            }
            #pragma unroll
            for (int ni = 0; ni < 4; ++ni) {
                const short8 b = *reinterpret_cast<const short8*>(
                    Wm1T + (size_t)(nc * 64 + ni * 16 + l15) * 192 + (ks * 4 + l4) * 8);
                #pragma unroll
                for (int mi = 0; mi < 4; ++mi)
                    hacc[mi][ni] = MFMA16(af[mi], b, hacc[mi][ni]);
            }
        }
        // silu(+bm1) -> hs (bf16, swizzled)
        #pragma unroll
        for (int ni = 0; ni < 4; ++ni) {
            const int col = nc * 64 + ni * 16 + l15;
            const float bb = bm1[col];
            #pragma unroll
            for (int mi = 0; mi < 4; ++mi) {
                #pragma unroll
                for (int j = 0; j < 4; ++j) {
                    const int r  = mi * 16 + l4 * 4 + j;
                    const int ch = (col >> 3) ^ (r & 7);
                    hs[r * 768 + ch * 8 + (col & 7)] =
                        __float2bfloat16(silu_f(hacc[mi][ni][j] + bb));
                }
            }
        }
    }
    __syncthreads();

    // ---- phase 2: final 48 cols per wave, K=768 ----
    const int c0w = wv * 48;
    f32x4 facc[4][3] = {};
    for (int ks = 0; ks < 24; ++ks) {
        short8 ha[4];
        #pragma unroll
        for (int mi = 0; mi < 4; ++mi) {
            const int r  = mi * 16 + l15;
            const int ch = (ks * 4 + l4) ^ (r & 7);
            ha[mi] = *reinterpret_cast<const short8*>(&hs[r * 768 + ch * 8]);
        }
        #pragma unroll
        for (int ni = 0; ni < 3; ++ni) {
            const short8 b = *reinterpret_cast<const short8*>(
                Wm2T + (size_t)(c0w + ni * 16 + l15) * 768 + ks * 32 + l4 * 8);
            #pragma unroll
            for (int mi = 0; mi < 4; ++mi)
                facc[mi][ni] = MFMA16(ha[mi], b, facc[mi][ni]);
        }
    }

    // epilogue: + bm2 + ob residual (from LDS), fp32 out
    #pragma unroll
    for (int ni = 0; ni < 3; ++ni) {
        const int col = c0w + ni * 16 + l15;
        const float b2 = bm2[col];
        #pragma unroll
        for (int mi = 0; mi < 4; ++mi) {
            #pragma unroll
            for (int j = 0; j < 4; ++j) {
                const int r  = mi * 16 + l4 * 4 + j;
                const int ch = (col >> 3) ^ (r & 7);
                const float resid = bf2f(*reinterpret_cast<const short*>(
                    &obs[r * 192 + ch * 8 + (col & 7)]));
                out[(size_t)(m0 + r) * 192 + col] = facc[mi][ni][j] + b2 + resid;
            }
        }
    }
}

// ---------------------------------------------------------------------------
// Depthwise 3x3 conv + bias + silu, gated (dense streams).
// ---------------------------------------------------------------------------
__launch_bounds__(256)
__global__ void dwconv_gate_v6(const bf16* __restrict__ x1, const bf16* __restrict__ sz,
                               const float* __restrict__ wT, const float* __restrict__ conv_b,
                               bf16* __restrict__ y)
{
    const int bid = blockIdx.x;
    const int swz = (bid & 7) * ((int)gridDim.x >> 3) + (bid >> 3);
    const int f   = swz * 256 + threadIdx.x;
    const int m   = f / 48;
    const int cg  = f - m * 48;
    const int c0  = cg * 8;
    const int h   = (m >> 6) & 63;
    const int w   = m & 63;

    float acc[8];
    {
        const f32x4 ba = *reinterpret_cast<const f32x4*>(&conv_b[c0]);
        const f32x4 bb = *reinterpret_cast<const f32x4*>(&conv_b[c0 + 4]);
        acc[0] = ba[0]; acc[1] = ba[1]; acc[2] = ba[2]; acc[3] = ba[3];
        acc[4] = bb[0]; acc[5] = bb[1]; acc[6] = bb[2]; acc[7] = bb[3];
    }

    #pragma unroll
    for (int r = 0; r < 3; ++r) {
        const int hh = h + r - 1;
        if (hh < 0 || hh >= HDIM) continue;
        #pragma unroll
        for (int dw = 0; dw < 3; ++dw) {
            const int ww = w + dw - 1;
            if (ww < 0 || ww >= WDIM) continue;
            const int mm  = m + (r - 1) * WDIM + (dw - 1);
            const int tap = r * 3 + dw;
            const short8 t = *reinterpret_cast<const short8*>(&x1[(size_t)mm * CIDIM + c0]);
            const f32x4 wa = *reinterpret_cast<const f32x4*>(&wT[tap * CIDIM + c0]);
            const f32x4 wb = *reinterpret_cast<const f32x4*>(&wT[tap * CIDIM + c0 + 4]);
            acc[0] += bf2f(t[0]) * wa[0]; acc[1] += bf2f(t[1]) * wa[1];
            acc[2] += bf2f(t[2]) * wa[2]; acc[3] += bf2f(t[3]) * wa[3];
            acc[4] += bf2f(t[4]) * wb[0]; acc[5] += bf2f(t[5]) * wb[1];
            acc[6] += bf2f(t[6]) * wb[2]; acc[7] += bf2f(t[7]) * wb[3];
        }
    }

    const short8 g = *reinterpret_cast<const short8*>(&sz[(size_t)m * CIDIM + c0]);
    bf16 tmp[8];
    #pragma unroll
    for (int j = 0; j < 8; ++j)
        tmp[j] = __float2bfloat16(silu_f(acc[j]) * bf2f(g[j]));
    *reinterpret_cast<short8*>(&y[(size_t)m * CIDIM + c0]) =
        *reinterpret_cast<const short8*>(tmp);
}

// ---------------------------------------------------------------------------
// ALL preprocessing in ONE launch.
// ---------------------------------------------------------------------------
#define SZ_WIN  (192 * 768)
#define SZ_WOUT (384 * 192)
#define SZ_WM1  (192 * 768)
#define SZ_WM2  (768 * 192)
#define SZ_CW   (CIDIM * 9)
#define XCVT    (MTOK * CDIM / 4)
#define SZ_ALL  (XCVT + SZ_WIN + SZ_WOUT + SZ_WM1 + SZ_WM2 + SZ_CW)

__launch_bounds__(256)
__global__ void prep_all(const float* __restrict__ x, const float* __restrict__ Win,
                         const float* __restrict__ Wout, const float* __restrict__ Wm1,
                         const float* __restrict__ Wm2, const float* __restrict__ convw,
                         bf16* __restrict__ xb, bf16* __restrict__ WinT,
                         bf16* __restrict__ WoutT, bf16* __restrict__ Wm1T,
                         bf16* __restrict__ Wm2T, float* __restrict__ wTc)
{
    int idx = blockIdx.x * 256 + threadIdx.x;
    if (idx < XCVT) {
        const int i = idx * 4;
        const float4 v = *reinterpret_cast<const float4*>(&x[i]);
        xb[i + 0] = __float2bfloat16(v.x);
        xb[i + 1] = __float2bfloat16(v.y);
        xb[i + 2] = __float2bfloat16(v.z);
        xb[i + 3] = __float2bfloat16(v.w);
        return;
    }
    idx -= XCVT;
    if (idx < SZ_WIN) {
        const int r = idx / 768, c = idx % 768;
        WinT[(size_t)c * 192 + r] = __float2bfloat16(Win[idx]);
        return;
    }
    idx -= SZ_WIN;
    if (idx < SZ_WOUT) {
        const int r = idx / 192, c = idx % 192;
        WoutT[(size_t)c * 384 + r] = __float2bfloat16(Wout[idx]);
        return;
    }
    idx -= SZ_WOUT;
    if (idx < SZ_WM1) {
        const int r = idx / 768, c = idx % 768;
        Wm1T[(size_t)c * 192 + r] = __float2bfloat16(Wm1[idx]);
        return;
    }
    idx -= SZ_WM1;
    if (idx < SZ_WM2) {
        const int r = idx / 192, c = idx % 192;
        Wm2T[(size_t)c * 768 + r] = __float2bfloat16(Wm2[idx]);
        return;
    }
    idx -= SZ_WM2;
    if (idx < SZ_CW) {
        const int ci = idx / 9, t = idx % 9;
        wTc[t * CIDIM + ci] = convw[idx];
    }
}

// ---------------------------------------------------------------------------
extern "C" void kernel_launch(void* const* d_in, const int* in_sizes, int n_in,
                              void* d_out, int out_size, void* d_ws, size_t ws_size,
                              hipStream_t stream)
{
    const float* x      = (const float*)d_in[0];
    const float* Win    = (const float*)d_in[1];
    const float* conv_w = (const float*)d_in[2];
    const float* conv_b = (const float*)d_in[3];
    const float* Wout   = (const float*)d_in[4];
    const float* Wm1    = (const float*)d_in[5];
    const float* bm1    = (const float*)d_in[6];
    const float* Wm2    = (const float*)d_in[7];
    const float* bm2    = (const float*)d_in[8];
    float* out = (float*)d_out;

    char* ws = (char*)d_ws;
    size_t o = 0;
    bf16*  xb    = (bf16*)(ws + o); o += (size_t)MTOK * CDIM * 2;
    bf16*  WinT  = (bf16*)(ws + o); o += (size_t)768 * 192 * 2;
    bf16*  WoutT = (bf16*)(ws + o); o += (size_t)192 * 384 * 2;
    bf16*  Wm1T  = (bf16*)(ws + o); o += (size_t)768 * 192 * 2;
    bf16*  Wm2T  = (bf16*)(ws + o); o += (size_t)192 * 768 * 2;
    float* wTc   = (float*)(ws + o); o += (size_t)9 * CIDIM * 4;
    bf16*  ws_x1 = (bf16*)(ws + o); o += (size_t)MTOK * CIDIM * 2;
    bf16*  ws_sz = (bf16*)(ws + o); o += (size_t)MTOK * CIDIM * 2;
    bf16*  ws_y  = (bf16*)(ws + o); o += (size_t)MTOK * CIDIM * 2;
    bf16*  ws_ob = (bf16*)(ws + o); o += (size_t)MTOK * CDIM * 2;

    // 0) all conversions/transposes in one launch
    prep_all<<<dim3((SZ_ALL + 255) / 256), dim3(256), 0, stream>>>(
        x, Win, Wout, Wm1, Wm2, conv_w, xb, WinT, WoutT, Wm1T, Wm2T, wTc);

    // 1) xz = x @ Win  [M,768], K=192 -> split dense x1 / sz(=4*silu(z))
    gemm_k192_p<0><<<dim3(12 * NSTRIPE), dim3(256), 0, stream>>>(
        xb, WinT, nullptr, ws_x1, ws_sz);

    // 2) y = silu(dwconv(x1)+b) * sz -> bf16
    dwconv_gate_v6<<<dim3(MTOK * 48 / 256), dim3(256), 0, stream>>>(
        ws_x1, ws_sz, wTc, conv_b, ws_y);

    // 3) out = x + y @ Wout   [M,192], K=384 -> bf16 ob
    gemm_mfma<1><<<dim3(3 * 256), dim3(256), 0, stream>>>(
        ws_y, WoutT, x, ws_ob, MTOK, CDIM, CIDIM, 3);

    // 4+5) final = ob + silu(ob@Wm1+bm1)@Wm2 + bm2  -> fp32 out (FUSED)
    fused_mlp<<<dim3(MTOK / 64), dim3(256), 0, stream>>>(
        ws_ob, Wm1T, Wm2T, bm1, bm2, out);
}

// Round 14
// 126.778 us; speedup vs baseline: 1.6727x; 1.0810x over previous
//
#include <hip/hip_runtime.h>
#include <hip/hip_bf16.h>

// Problem constants
#define BDIM 8
#define HDIM 64
#define WDIM 64
#define CDIM 192
#define CIDIM 384
#define MTOK (BDIM * HDIM * WDIM)   // 32768 tokens

using bf16 = __hip_bfloat16;
typedef __attribute__((ext_vector_type(8))) short short8;   // 8 bf16 (4 VGPRs)
typedef __attribute__((ext_vector_type(4))) float f32x4;

__device__ __forceinline__ float silu_f(float v) { return v / (1.0f + __expf(-v)); }
__device__ __forceinline__ float bf2f(short s) {
    union { unsigned u; float f; } x; x.u = ((unsigned)(unsigned short)s) << 16; return x.f;
}

__device__ __forceinline__ void gload_lds16(const bf16* g, bf16* l) {
    __builtin_amdgcn_global_load_lds(
        (const __attribute__((address_space(1))) void*)g,
        (__attribute__((address_space(3))) void*)l, 16, 0, 0);
}

#define MFMA16(a, b, c) __builtin_amdgcn_mfma_f32_16x16x32_bf16(a, b, c, 0, 0, 0)

// ---------------------------------------------------------------------------
// FULL-K ONE-BARRIER GEMM for K=192 (G1, G4): C = A[M,192] @ B, B given
// TRANSPOSED [N,192], N=768 = 12 n-tiles. BM=128, BN=64.
// Stage A(48KB)+B(24KB)=72KB once (18 gload_lds/thread), ONE barrier, then
// 4 waves x (64x32 tile, 4x2 frags): 6 ks x {6 ds_read + 8 MFMA} = 48 MFMA
// free-running; stores at kernel end (no barrier after -> off critical path).
// 2 blocks/CU; ~12-block queue/CU overlaps staging with compute.
// Grid 3072 XCD-chunked, n-fastest: xcd=bid&7 owns 32 m-panels x 12 n-tiles;
// A panel's 12 consumers hit one XCD's L2; B (288KB/XCD) L2-resident.
// Row = 24 x 16B slots; physical slot p of row r holds logical p^(r&7).
// EPI 0: nt<6 -> outB (x1, stride 384); nt>=6 -> outB2 = 4*silu(v)   [G1]
// EPI 2: silu(v+bias) -> outB, stride 768                             [G4]
// ---------------------------------------------------------------------------
template <int EPI>
__launch_bounds__(256, 2)
__global__ void gemm_k192_f(const bf16* __restrict__ A, const bf16* __restrict__ BT,
                            const float* __restrict__ bias,
                            bf16* __restrict__ outB, bf16* __restrict__ outB2)
{
    __shared__ bf16 As[128 * 192];   // 48 KB
    __shared__ bf16 Bs[64 * 192];    // 24 KB

    const int bid = blockIdx.x;
    const int xcd = bid & 7;
    const int t_  = bid >> 3;            // 0..383
    const int mp  = xcd * 32 + t_ / 12;  // m-panel 0..255
    const int nt  = t_ % 12;
    const int m0  = mp * 128;
    const int n0  = nt * 64;

    const int tid  = threadIdx.x;
    const int lane = tid & 63;
    const int wv   = tid >> 6;
    const int wm   = wv >> 1;
    const int wn   = wv & 1;
    const int l15  = lane & 15;
    const int l4   = lane >> 4;

    // --- stage 72KB: 72 wave-chunks (A: 0..47, B: 48..71), 18 per wave ---
    #pragma unroll
    for (int i = 0; i < 18; ++i) {
        const int ci = wv * 18 + i;          // wave-instr id 0..71
        const int c  = ci * 64 + lane;       // 16B-chunk id
        if (ci < 48) {                        // A region (3072 chunks)
            const int row  = c / 24;
            const int slot = c - row * 24;
            gload_lds16(A + (size_t)(m0 + row) * 192 + ((slot ^ (row & 7)) << 3),
                        &As[ci * 512]);
        } else {                              // B region (1536 chunks)
            const int c2   = c - 3072;
            const int row  = c2 / 24;
            const int slot = c2 - row * 24;
            gload_lds16(BT + (size_t)(n0 + row) * 192 + ((slot ^ (row & 7)) << 3),
                        &Bs[(ci - 48) * 512]);
        }
    }
    __syncthreads();   // the ONLY barrier

    // --- compute: wave tile 64(m) x 32(n), 4x2 frags, 48 MFMA ---
    f32x4 acc[4][2] = {};
    #pragma unroll
    for (int ks = 0; ks < 6; ++ks) {
        const int t = ks * 4 + l4;
        short8 af[4], bfr[2];
        #pragma unroll
        for (int mi = 0; mi < 4; ++mi) {
            const int m = wm * 64 + mi * 16 + l15;
            af[mi] = *reinterpret_cast<const short8*>(&As[m * 192 + ((t ^ (m & 7)) << 3)]);
        }
        #pragma unroll
        for (int ni = 0; ni < 2; ++ni) {
            const int n = wn * 32 + ni * 16 + l15;
            bfr[ni] = *reinterpret_cast<const short8*>(&Bs[n * 192 + ((t ^ (n & 7)) << 3)]);
        }
        #pragma unroll
        for (int mi = 0; mi < 4; ++mi)
            #pragma unroll
            for (int ni = 0; ni < 2; ++ni)
                acc[mi][ni] = MFMA16(af[mi], bfr[ni], acc[mi][ni]);
    }

    // --- epilogue: direct stores (no barrier follows -> fully async) ---
    const bool isZ   = (EPI == 0) && (nt >= 6);
    bf16* dst        = (EPI == 0) ? (isZ ? outB2 : outB) : outB;
    const int stride = (EPI == 0) ? CIDIM : 768;
    const int col0   = (EPI == 0) ? (isZ ? n0 - CIDIM : n0) : n0;

    const int rowb = m0 + wm * 64 + l4 * 4;
    const int colb = col0 + wn * 32 + l15;
    #pragma unroll
    for (int mi = 0; mi < 4; ++mi) {
        #pragma unroll
        for (int ni = 0; ni < 2; ++ni) {
            const int c = colb + ni * 16;
            #pragma unroll
            for (int j = 0; j < 4; ++j) {
                const int row = rowb + mi * 16 + j;
                float v = acc[mi][ni][j];
                if constexpr (EPI == 0) {
                    if (isZ) v = 4.0f * silu_f(v);
                } else {
                    v = silu_f(v + bias[n0 + (c - col0)]);
                }
                dst[(size_t)row * stride + c] = __float2bfloat16(v);
            }
        }
    }
}

// ---------------------------------------------------------------------------
// Loop GEMM (K=384/768): BM=128, BN=64, BK=64. 4 waves 2x2; wave 64x32.
// 1D grid + XCD-bijective swizzle (y%8 == bid%8).
// EPI 1: +residF(fp32) -> outB bf16 only                              [G3]
// EPI 3: v + bias + bf2f(residB) -> outF fp32                         [G5]
// ---------------------------------------------------------------------------
template <int EPI>
__launch_bounds__(256, 4)
__global__ void gemm_mfma(const bf16* __restrict__ A, const bf16* __restrict__ BT,
                          const float* __restrict__ bias,
                          const float* __restrict__ residF,
                          const bf16* __restrict__ residB,
                          float* __restrict__ outF, bf16* __restrict__ outB,
                          int M, int N, int K, int NX)
{
    __shared__ bf16 As[128 * 64];
    __shared__ bf16 Bs[64 * 64];

    const int bid = blockIdx.x;
    const int c8  = bid & 7;
    const int kq  = bid >> 3;
    const int bx  = kq % NX;
    const int by  = (kq / NX) * 8 + c8;
    const int m0  = by * 128;
    const int n0  = bx * 64;

    const int tid  = threadIdx.x;
    const int lane = tid & 63;
    const int wv   = tid >> 6;
    const int wm   = wv >> 1;
    const int wn   = wv & 1;

    const int srow  = lane >> 3;
    const int sslot = lane & 7;

    f32x4 acc[4][2] = {};

    for (int k0 = 0; k0 < K; k0 += 64) {
        #pragma unroll
        for (int i = 0; i < 4; ++i) {
            const int rb = wv * 32 + i * 8;
            const int r  = rb + srow;
            gload_lds16(A + (size_t)(m0 + r) * K + k0 + ((sslot ^ (r & 7)) << 3),
                        &As[rb * 64]);
        }
        #pragma unroll
        for (int i = 0; i < 2; ++i) {
            const int rb = wv * 16 + i * 8;
            const int r  = rb + srow;
            gload_lds16(BT + (size_t)(n0 + r) * K + k0 + ((sslot ^ (r & 7)) << 3),
                        &Bs[rb * 64]);
        }
        __syncthreads();

        #pragma unroll
        for (int kk = 0; kk < 2; ++kk) {
            const int t = kk * 4 + (lane >> 4);
            short8 af[4], bfr[2];
            #pragma unroll
            for (int mi = 0; mi < 4; ++mi) {
                const int m = wm * 64 + mi * 16 + (lane & 15);
                af[mi] = *reinterpret_cast<const short8*>(&As[m * 64 + ((t ^ (m & 7)) << 3)]);
            }
            #pragma unroll
            for (int ni = 0; ni < 2; ++ni) {
                const int n = wn * 32 + ni * 16 + (lane & 15);
                bfr[ni] = *reinterpret_cast<const short8*>(&Bs[n * 64 + ((t ^ (n & 7)) << 3)]);
            }
            #pragma unroll
            for (int mi = 0; mi < 4; ++mi)
                #pragma unroll
                for (int ni = 0; ni < 2; ++ni)
                    acc[mi][ni] = MFMA16(af[mi], bfr[ni], acc[mi][ni]);
        }
        __syncthreads();
    }

    const int colb = n0 + wn * 32 + (lane & 15);
    const int rowb = m0 + wm * 64 + (lane >> 4) * 4;
    #pragma unroll
    for (int mi = 0; mi < 4; ++mi) {
        #pragma unroll
        for (int ni = 0; ni < 2; ++ni) {
            const int c = colb + ni * 16;
            #pragma unroll
            for (int j = 0; j < 4; ++j) {
                const int row = rowb + mi * 16 + j;
                const size_t off = (size_t)row * N + c;
                const float v = acc[mi][ni][j];
                if constexpr (EPI == 1) {
                    outB[off] = __float2bfloat16(v + residF[off]);
                } else {
                    outF[off] = v + bias[c] + bf2f(*(const short*)&residB[off]);
                }
            }
        }
    }
}

// ---------------------------------------------------------------------------
// Depthwise 3x3 conv + bias + silu, gated (dense streams).
// ---------------------------------------------------------------------------
__launch_bounds__(256)
__global__ void dwconv_gate_v6(const bf16* __restrict__ x1, const bf16* __restrict__ sz,
                               const float* __restrict__ wT, const float* __restrict__ conv_b,
                               bf16* __restrict__ y)
{
    const int bid = blockIdx.x;
    const int swz = (bid & 7) * ((int)gridDim.x >> 3) + (bid >> 3);
    const int f   = swz * 256 + threadIdx.x;
    const int m   = f / 48;
    const int cg  = f - m * 48;
    const int c0  = cg * 8;
    const int h   = (m >> 6) & 63;
    const int w   = m & 63;

    float acc[8];
    {
        const f32x4 ba = *reinterpret_cast<const f32x4*>(&conv_b[c0]);
        const f32x4 bb = *reinterpret_cast<const f32x4*>(&conv_b[c0 + 4]);
        acc[0] = ba[0]; acc[1] = ba[1]; acc[2] = ba[2]; acc[3] = ba[3];
        acc[4] = bb[0]; acc[5] = bb[1]; acc[6] = bb[2]; acc[7] = bb[3];
    }

    #pragma unroll
    for (int r = 0; r < 3; ++r) {
        const int hh = h + r - 1;
        if (hh < 0 || hh >= HDIM) continue;
        #pragma unroll
        for (int dw = 0; dw < 3; ++dw) {
            const int ww = w + dw - 1;
            if (ww < 0 || ww >= WDIM) continue;
            const int mm  = m + (r - 1) * WDIM + (dw - 1);
            const int tap = r * 3 + dw;
            const short8 t = *reinterpret_cast<const short8*>(&x1[(size_t)mm * CIDIM + c0]);
            const f32x4 wa = *reinterpret_cast<const f32x4*>(&wT[tap * CIDIM + c0]);
            const f32x4 wb = *reinterpret_cast<const f32x4*>(&wT[tap * CIDIM + c0 + 4]);
            acc[0] += bf2f(t[0]) * wa[0]; acc[1] += bf2f(t[1]) * wa[1];
            acc[2] += bf2f(t[2]) * wa[2]; acc[3] += bf2f(t[3]) * wa[3];
            acc[4] += bf2f(t[4]) * wb[0]; acc[5] += bf2f(t[5]) * wb[1];
            acc[6] += bf2f(t[6]) * wb[2]; acc[7] += bf2f(t[7]) * wb[3];
        }
    }

    const short8 g = *reinterpret_cast<const short8*>(&sz[(size_t)m * CIDIM + c0]);
    bf16 tmp[8];
    #pragma unroll
    for (int j = 0; j < 8; ++j)
        tmp[j] = __float2bfloat16(silu_f(acc[j]) * bf2f(g[j]));
    *reinterpret_cast<short8*>(&y[(size_t)m * CIDIM + c0]) =
        *reinterpret_cast<const short8*>(tmp);
}

// ---------------------------------------------------------------------------
// ALL preprocessing in ONE launch.
// ---------------------------------------------------------------------------
#define SZ_WIN  (192 * 768)
#define SZ_WOUT (384 * 192)
#define SZ_WM1  (192 * 768)
#define SZ_WM2  (768 * 192)
#define SZ_CW   (CIDIM * 9)
#define XCVT    (MTOK * CDIM / 4)
#define SZ_ALL  (XCVT + SZ_WIN + SZ_WOUT + SZ_WM1 + SZ_WM2 + SZ_CW)

__launch_bounds__(256)
__global__ void prep_all(const float* __restrict__ x, const float* __restrict__ Win,
                         const float* __restrict__ Wout, const float* __restrict__ Wm1,
                         const float* __restrict__ Wm2, const float* __restrict__ convw,
                         bf16* __restrict__ xb, bf16* __restrict__ WinT,
                         bf16* __restrict__ WoutT, bf16* __restrict__ Wm1T,
                         bf16* __restrict__ Wm2T, float* __restrict__ wTc)
{
    int idx = blockIdx.x * 256 + threadIdx.x;
    if (idx < XCVT) {
        const int i = idx * 4;
        const float4 v = *reinterpret_cast<const float4*>(&x[i]);
        xb[i + 0] = __float2bfloat16(v.x);
        xb[i + 1] = __float2bfloat16(v.y);
        xb[i + 2] = __float2bfloat16(v.z);
        xb[i + 3] = __float2bfloat16(v.w);
        return;
    }
    idx -= XCVT;
    if (idx < SZ_WIN) {
        const int r = idx / 768, c = idx % 768;
        WinT[(size_t)c * 192 + r] = __float2bfloat16(Win[idx]);
        return;
    }
    idx -= SZ_WIN;
    if (idx < SZ_WOUT) {
        const int r = idx / 192, c = idx % 192;
        WoutT[(size_t)c * 384 + r] = __float2bfloat16(Wout[idx]);
        return;
    }
    idx -= SZ_WOUT;
    if (idx < SZ_WM1) {
        const int r = idx / 768, c = idx % 768;
        Wm1T[(size_t)c * 192 + r] = __float2bfloat16(Wm1[idx]);
        return;
    }
    idx -= SZ_WM1;
    if (idx < SZ_WM2) {
        const int r = idx / 192, c = idx % 192;
        Wm2T[(size_t)c * 768 + r] = __float2bfloat16(Wm2[idx]);
        return;
    }
    idx -= SZ_WM2;
    if (idx < SZ_CW) {
        const int ci = idx / 9, t = idx % 9;
        wTc[t * CIDIM + ci] = convw[idx];
    }
}

// ---------------------------------------------------------------------------
extern "C" void kernel_launch(void* const* d_in, const int* in_sizes, int n_in,
                              void* d_out, int out_size, void* d_ws, size_t ws_size,
                              hipStream_t stream)
{
    const float* x      = (const float*)d_in[0];
    const float* Win    = (const float*)d_in[1];
    const float* conv_w = (const float*)d_in[2];
    const float* conv_b = (const float*)d_in[3];
    const float* Wout   = (const float*)d_in[4];
    const float* Wm1    = (const float*)d_in[5];
    const float* bm1    = (const float*)d_in[6];
    const float* Wm2    = (const float*)d_in[7];
    const float* bm2    = (const float*)d_in[8];
    float* out = (float*)d_out;

    char* ws = (char*)d_ws;
    size_t o = 0;
    bf16*  xb    = (bf16*)(ws + o); o += (size_t)MTOK * CDIM * 2;
    bf16*  WinT  = (bf16*)(ws + o); o += (size_t)768 * 192 * 2;
    bf16*  WoutT = (bf16*)(ws + o); o += (size_t)192 * 384 * 2;
    bf16*  Wm1T  = (bf16*)(ws + o); o += (size_t)768 * 192 * 2;
    bf16*  Wm2T  = (bf16*)(ws + o); o += (size_t)192 * 768 * 2;
    float* wTc   = (float*)(ws + o); o += (size_t)9 * CIDIM * 4;
    bf16*  ws_x1 = (bf16*)(ws + o); o += (size_t)MTOK * CIDIM * 2;   // dense x1 [M,384]
    bf16*  ws_sz = (bf16*)(ws + o); o += (size_t)MTOK * CIDIM * 2;   // dense 4*silu(z)
    bf16*  ws_y  = (bf16*)(ws + o); o += (size_t)MTOK * CIDIM * 2;
    bf16*  ws_ob = (bf16*)(ws + o); o += (size_t)MTOK * CDIM * 2;    // out bf16 [M,192]
    bf16*  ws_h  = ws_x1;   // G4 output [M,768] reuses x1+sz region (dead by then)

    // 0) all conversions/transposes in one launch
    prep_all<<<dim3((SZ_ALL + 255) / 256), dim3(256), 0, stream>>>(
        x, Win, Wout, Wm1, Wm2, conv_w, xb, WinT, WoutT, Wm1T, Wm2T, wTc);

    // 1) xz = x @ Win  [M,768], K=192 -> split dense x1 / sz(=4*silu(z))
    //    full-K one-barrier, BM=128
    gemm_k192_f<0><<<dim3(3072), dim3(256), 0, stream>>>(
        xb, WinT, nullptr, ws_x1, ws_sz);

    // 2) y = silu(dwconv(x1)+b) * sz -> bf16
    dwconv_gate_v6<<<dim3(MTOK * 48 / 256), dim3(256), 0, stream>>>(
        ws_x1, ws_sz, wTc, conv_b, ws_y);

    // 3) out = x + y @ Wout   [M,192], K=384 -> bf16 ob
    gemm_mfma<1><<<dim3(3 * 256), dim3(256), 0, stream>>>(
        ws_y, WoutT, nullptr, x, nullptr, nullptr, ws_ob, MTOK, CDIM, CIDIM, 3);

    // 4) h = silu(out @ Wm1 + bm1)   [M,768], K=192 -> bf16 (full-K one-barrier)
    gemm_k192_f<2><<<dim3(3072), dim3(256), 0, stream>>>(
        ws_ob, Wm1T, bm1, ws_h, nullptr);

    // 5) final = bf16(out) + h @ Wm2 + bm2   [M,192], K=768 -> fp32
    gemm_mfma<3><<<dim3(3 * 256), dim3(256), 0, stream>>>(
        ws_h, Wm2T, bm2, nullptr, ws_ob, out, nullptr, MTOK, CDIM, 768, 3);
}

// Round 15
// 122.588 us; speedup vs baseline: 1.7298x; 1.0342x over previous
//
#include <hip/hip_runtime.h>
#include <hip/hip_bf16.h>

// Problem constants
#define BDIM 8
#define HDIM 64
#define WDIM 64
#define CDIM 192
#define CIDIM 384
#define MTOK (BDIM * HDIM * WDIM)   // 32768 tokens

using bf16 = __hip_bfloat16;
typedef __attribute__((ext_vector_type(8))) short short8;   // 8 bf16 (4 VGPRs)
typedef __attribute__((ext_vector_type(4))) float f32x4;

__device__ __forceinline__ float silu_f(float v) { return v / (1.0f + __expf(-v)); }
__device__ __forceinline__ float bf2f(short s) {
    union { unsigned u; float f; } x; x.u = ((unsigned)(unsigned short)s) << 16; return x.f;
}

__device__ __forceinline__ void gload_lds16(const bf16* g, bf16* l) {
    __builtin_amdgcn_global_load_lds(
        (const __attribute__((address_space(1))) void*)g,
        (__attribute__((address_space(3))) void*)l, 16, 0, 0);
}

#define MFMA16(a, b, c) __builtin_amdgcn_mfma_f32_16x16x32_bf16(a, b, c, 0, 0, 0)

// ---------------------------------------------------------------------------
// PERSISTENT K=192 GEMM (G1, G4) with TRUE async prefetch (T3+T4):
// B staged once (24KB); A double-buffered (2x24KB). Per iter:
//   {stage A[t+1] -> buf^1 ; s_waitcnt vmcnt(6) [waits ONLY tile-t's loads,
//    issued one iter ago — NOT the fresh prefetch] ; raw s_barrier ; compute ;
//    raw s_barrier ; stores}.
// __syncthreads would emit vmcnt(0) before s_barrier and drain the prefetch
// (the documented structural stall) — raw barriers + counted vmcnt avoid it.
// Last iter: no new stage -> vmcnt(0) (counted wait would pass early).
// Grid 480 = 12 n x 40 stripes; bid%8 = s%8 -> A panel pinned to one XCD L2.
// Row = 24 x 16B slots; physical slot p of row r holds logical p^(r&7).
// EPI 0: split c<384 -> outB (x1, stride 384); else outB2 = 4*silu(v)  [G1]
// EPI 2: silu(v+bias) -> outB, stride 768                              [G4]
// ---------------------------------------------------------------------------
#define NSTRIPE 40
template <int EPI>
__launch_bounds__(256, 2)
__global__ void gemm_k192_p(const bf16* __restrict__ A, const bf16* __restrict__ BT,
                            const float* __restrict__ bias,
                            bf16* __restrict__ outB, bf16* __restrict__ outB2)
{
    __shared__ bf16 As[2][64 * 192];   // 48 KB (double-buffered A)
    __shared__ bf16 Bs[64 * 192];      // 24 KB (resident B n-tile)

    const int bid = blockIdx.x;
    const int n   = bid / NSTRIPE;
    const int s   = bid % NSTRIPE;
    const int n0  = n * 64;

    const int tid  = threadIdx.x;
    const int lane = tid & 63;
    const int wv   = tid >> 6;
    const int wm   = wv >> 1;
    const int wn   = wv & 1;

    // m-invariant staging offsets (6 chunks per wave)
    int soff[6];
    #pragma unroll
    for (int i = 0; i < 6; ++i) {
        const int ci   = wv * 6 + i;
        const int c    = ci * 64 + lane;
        const int row  = c / 24;
        const int slot = c - row * 24;
        soff[i] = row * 192 + (slot ^ (row & 7)) * 8;
    }

    // prologue: stage B + first A tile (12 loads outstanding)
    #pragma unroll
    for (int i = 0; i < 6; ++i)
        gload_lds16(BT + (size_t)n0 * 192 + soff[i], &Bs[(wv * 6 + i) * 512]);
    #pragma unroll
    for (int i = 0; i < 6; ++i)
        gload_lds16(A + (size_t)(s * 64) * 192 + soff[i], &As[0][(wv * 6 + i) * 512]);

    const int mloc[2] = { wm * 32 + (lane & 15), wm * 32 + 16 + (lane & 15) };
    const int nloc[2] = { wn * 32 + (lane & 15), wn * 32 + 16 + (lane & 15) };
    const bool isZ = (EPI == 0) && (n0 >= CIDIM);
    bf16* dst        = (EPI == 0) ? (isZ ? outB2 : outB) : outB;
    const int stride = (EPI == 0) ? CIDIM : 768;
    const int col0   = (EPI == 0) ? (isZ ? n0 - CIDIM : n0) : n0;

    int cur = 0;
    for (int mt = s; mt < 512; mt += NSTRIPE) {
        const int nmt = mt + NSTRIPE;
        if (nmt < 512) {
            // prefetch next A tile into the buffer computed LAST iteration
            const bf16* a1 = A + (size_t)(nmt * 64) * 192;
            bf16* db = As[cur ^ 1];
            #pragma unroll
            for (int i = 0; i < 6; ++i)
                gload_lds16(a1 + soff[i], &db[(wv * 6 + i) * 512]);
            // wait only for tile-t's loads (6 newest = the fresh prefetch stay in flight)
            asm volatile("s_waitcnt vmcnt(6)" ::: "memory");
        } else {
            asm volatile("s_waitcnt vmcnt(0)" ::: "memory");
        }
        __builtin_amdgcn_sched_barrier(0);
        __builtin_amdgcn_s_barrier();          // raw: no vmcnt(0) drain
        __builtin_amdgcn_sched_barrier(0);

        // compute: wave tile 32x32, 6 k-steps, 24 MFMA
        const bf16* la = As[cur];
        f32x4 acc[2][2] = {};
        __builtin_amdgcn_s_setprio(1);
        #pragma unroll
        for (int ks = 0; ks < 6; ++ks) {
            const int t = ks * 4 + (lane >> 4);
            short8 af[2], bfr[2];
            #pragma unroll
            for (int mi = 0; mi < 2; ++mi) {
                const int m = mloc[mi];
                af[mi] = *reinterpret_cast<const short8*>(&la[m * 192 + ((t ^ (m & 7)) << 3)]);
            }
            #pragma unroll
            for (int ni = 0; ni < 2; ++ni) {
                const int nn = nloc[ni];
                bfr[ni] = *reinterpret_cast<const short8*>(&Bs[nn * 192 + ((t ^ (nn & 7)) << 3)]);
            }
            #pragma unroll
            for (int mi = 0; mi < 2; ++mi)
                #pragma unroll
                for (int ni = 0; ni < 2; ++ni)
                    acc[mi][ni] = MFMA16(af[mi], bfr[ni], acc[mi][ni]);
        }
        __builtin_amdgcn_s_setprio(0);

        __builtin_amdgcn_sched_barrier(0);
        __builtin_amdgcn_s_barrier();          // raw: As[cur] free for next prefetch
        __builtin_amdgcn_sched_barrier(0);

        // stores (read acc regs only — safe after barrier, off critical path)
        const int m0   = mt * 64;
        const int rowb = m0 + wm * 32 + (lane >> 4) * 4;
        const int colb = col0 + wn * 32 + (lane & 15);
        #pragma unroll
        for (int mi = 0; mi < 2; ++mi) {
            #pragma unroll
            for (int ni = 0; ni < 2; ++ni) {
                const int c = colb + ni * 16;
                #pragma unroll
                for (int j = 0; j < 4; ++j) {
                    const int row = rowb + mi * 16 + j;
                    float v = acc[mi][ni][j];
                    if constexpr (EPI == 0) {
                        if (isZ) v = 4.0f * silu_f(v);
                    } else {
                        v = silu_f(v + bias[n0 + (c - col0)]);
                    }
                    dst[(size_t)row * stride + c] = __float2bfloat16(v);
                }
            }
        }
        cur ^= 1;
    }
}

// ---------------------------------------------------------------------------
// Loop GEMM (K=384/768): BM=128, BN=64, BK=64. 4 waves 2x2; wave 64x32.
// 1D grid + XCD-bijective swizzle (y%8 == bid%8).
// EPI 1: + bf2f(residB) -> outB bf16                                  [G3]
// EPI 3: v + bias + bf2f(residB) -> outF fp32                         [G5]
// ---------------------------------------------------------------------------
template <int EPI>
__launch_bounds__(256, 4)
__global__ void gemm_mfma(const bf16* __restrict__ A, const bf16* __restrict__ BT,
                          const float* __restrict__ bias,
                          const bf16* __restrict__ residB,
                          float* __restrict__ outF, bf16* __restrict__ outB,
                          int M, int N, int K, int NX)
{
    __shared__ bf16 As[128 * 64];
    __shared__ bf16 Bs[64 * 64];

    const int bid = blockIdx.x;
    const int c8  = bid & 7;
    const int kq  = bid >> 3;
    const int bx  = kq % NX;
    const int by  = (kq / NX) * 8 + c8;
    const int m0  = by * 128;
    const int n0  = bx * 64;

    const int tid  = threadIdx.x;
    const int lane = tid & 63;
    const int wv   = tid >> 6;
    const int wm   = wv >> 1;
    const int wn   = wv & 1;

    const int srow  = lane >> 3;
    const int sslot = lane & 7;

    f32x4 acc[4][2] = {};

    for (int k0 = 0; k0 < K; k0 += 64) {
        #pragma unroll
        for (int i = 0; i < 4; ++i) {
            const int rb = wv * 32 + i * 8;
            const int r  = rb + srow;
            gload_lds16(A + (size_t)(m0 + r) * K + k0 + ((sslot ^ (r & 7)) << 3),
                        &As[rb * 64]);
        }
        #pragma unroll
        for (int i = 0; i < 2; ++i) {
            const int rb = wv * 16 + i * 8;
            const int r  = rb + srow;
            gload_lds16(BT + (size_t)(n0 + r) * K + k0 + ((sslot ^ (r & 7)) << 3),
                        &Bs[rb * 64]);
        }
        __syncthreads();

        #pragma unroll
        for (int kk = 0; kk < 2; ++kk) {
            const int t = kk * 4 + (lane >> 4);
            short8 af[4], bfr[2];
            #pragma unroll
            for (int mi = 0; mi < 4; ++mi) {
                const int m = wm * 64 + mi * 16 + (lane & 15);
                af[mi] = *reinterpret_cast<const short8*>(&As[m * 64 + ((t ^ (m & 7)) << 3)]);
            }
            #pragma unroll
            for (int ni = 0; ni < 2; ++ni) {
                const int n = wn * 32 + ni * 16 + (lane & 15);
                bfr[ni] = *reinterpret_cast<const short8*>(&Bs[n * 64 + ((t ^ (n & 7)) << 3)]);
            }
            #pragma unroll
            for (int mi = 0; mi < 4; ++mi)
                #pragma unroll
                for (int ni = 0; ni < 2; ++ni)
                    acc[mi][ni] = MFMA16(af[mi], bfr[ni], acc[mi][ni]);
        }
        __syncthreads();
    }

    const int colb = n0 + wn * 32 + (lane & 15);
    const int rowb = m0 + wm * 64 + (lane >> 4) * 4;
    #pragma unroll
    for (int mi = 0; mi < 4; ++mi) {
        #pragma unroll
        for (int ni = 0; ni < 2; ++ni) {
            const int c = colb + ni * 16;
            #pragma unroll
            for (int j = 0; j < 4; ++j) {
                const int row = rowb + mi * 16 + j;
                const size_t off = (size_t)row * N + c;
                const float v = acc[mi][ni][j];
                if constexpr (EPI == 1) {
                    outB[off] = __float2bfloat16(v + bf2f(*(const short*)&residB[off]));
                } else {
                    outF[off] = v + bias[c] + bf2f(*(const short*)&residB[off]);
                }
            }
        }
    }
}

// ---------------------------------------------------------------------------
// Depthwise 3x3 conv + bias + silu, gated (dense streams).
// ---------------------------------------------------------------------------
__launch_bounds__(256)
__global__ void dwconv_gate_v6(const bf16* __restrict__ x1, const bf16* __restrict__ sz,
                               const float* __restrict__ wT, const float* __restrict__ conv_b,
                               bf16* __restrict__ y)
{
    const int bid = blockIdx.x;
    const int swz = (bid & 7) * ((int)gridDim.x >> 3) + (bid >> 3);
    const int f   = swz * 256 + threadIdx.x;
    const int m   = f / 48;
    const int cg  = f - m * 48;
    const int c0  = cg * 8;
    const int h   = (m >> 6) & 63;
    const int w   = m & 63;

    float acc[8];
    {
        const f32x4 ba = *reinterpret_cast<const f32x4*>(&conv_b[c0]);
        const f32x4 bb = *reinterpret_cast<const f32x4*>(&conv_b[c0 + 4]);
        acc[0] = ba[0]; acc[1] = ba[1]; acc[2] = ba[2]; acc[3] = ba[3];
        acc[4] = bb[0]; acc[5] = bb[1]; acc[6] = bb[2]; acc[7] = bb[3];
    }

    #pragma unroll
    for (int r = 0; r < 3; ++r) {
        const int hh = h + r - 1;
        if (hh < 0 || hh >= HDIM) continue;
        #pragma unroll
        for (int dw = 0; dw < 3; ++dw) {
            const int ww = w + dw - 1;
            if (ww < 0 || ww >= WDIM) continue;
            const int mm  = m + (r - 1) * WDIM + (dw - 1);
            const int tap = r * 3 + dw;
            const short8 t = *reinterpret_cast<const short8*>(&x1[(size_t)mm * CIDIM + c0]);
            const f32x4 wa = *reinterpret_cast<const f32x4*>(&wT[tap * CIDIM + c0]);
            const f32x4 wb = *reinterpret_cast<const f32x4*>(&wT[tap * CIDIM + c0 + 4]);
            acc[0] += bf2f(t[0]) * wa[0]; acc[1] += bf2f(t[1]) * wa[1];
            acc[2] += bf2f(t[2]) * wa[2]; acc[3] += bf2f(t[3]) * wa[3];
            acc[4] += bf2f(t[4]) * wb[0]; acc[5] += bf2f(t[5]) * wb[1];
            acc[6] += bf2f(t[6]) * wb[2]; acc[7] += bf2f(t[7]) * wb[3];
        }
    }

    const short8 g = *reinterpret_cast<const short8*>(&sz[(size_t)m * CIDIM + c0]);
    bf16 tmp[8];
    #pragma unroll
    for (int j = 0; j < 8; ++j)
        tmp[j] = __float2bfloat16(silu_f(acc[j]) * bf2f(g[j]));
    *reinterpret_cast<short8*>(&y[(size_t)m * CIDIM + c0]) =
        *reinterpret_cast<const short8*>(tmp);
}

// ---------------------------------------------------------------------------
// ALL preprocessing in ONE launch.
// ---------------------------------------------------------------------------
#define SZ_WIN  (192 * 768)
#define SZ_WOUT (384 * 192)
#define SZ_WM1  (192 * 768)
#define SZ_WM2  (768 * 192)
#define SZ_CW   (CIDIM * 9)
#define XCVT    (MTOK * CDIM / 4)
#define SZ_ALL  (XCVT + SZ_WIN + SZ_WOUT + SZ_WM1 + SZ_WM2 + SZ_CW)

__launch_bounds__(256)
__global__ void prep_all(const float* __restrict__ x, const float* __restrict__ Win,
                         const float* __restrict__ Wout, const float* __restrict__ Wm1,
                         const float* __restrict__ Wm2, const float* __restrict__ convw,
                         bf16* __restrict__ xb, bf16* __restrict__ WinT,
                         bf16* __restrict__ WoutT, bf16* __restrict__ Wm1T,
                         bf16* __restrict__ Wm2T, float* __restrict__ wTc)
{
    int idx = blockIdx.x * 256 + threadIdx.x;
    if (idx < XCVT) {
        const int i = idx * 4;
        const float4 v = *reinterpret_cast<const float4*>(&x[i]);
        xb[i + 0] = __float2bfloat16(v.x);
        xb[i + 1] = __float2bfloat16(v.y);
        xb[i + 2] = __float2bfloat16(v.z);
        xb[i + 3] = __float2bfloat16(v.w);
        return;
    }
    idx -= XCVT;
    if (idx < SZ_WIN) {
        const int r = idx / 768, c = idx % 768;
        WinT[(size_t)c * 192 + r] = __float2bfloat16(Win[idx]);
        return;
    }
    idx -= SZ_WIN;
    if (idx < SZ_WOUT) {
        const int r = idx / 192, c = idx % 192;
        WoutT[(size_t)c * 384 + r] = __float2bfloat16(Wout[idx]);
        return;
    }
    idx -= SZ_WOUT;
    if (idx < SZ_WM1) {
        const int r = idx / 768, c = idx % 768;
        Wm1T[(size_t)c * 192 + r] = __float2bfloat16(Wm1[idx]);
        return;
    }
    idx -= SZ_WM1;
    if (idx < SZ_WM2) {
        const int r = idx / 192, c = idx % 192;
        Wm2T[(size_t)c * 768 + r] = __float2bfloat16(Wm2[idx]);
        return;
    }
    idx -= SZ_WM2;
    if (idx < SZ_CW) {
        const int ci = idx / 9, t = idx % 9;
        wTc[t * CIDIM + ci] = convw[idx];
    }
}

// ---------------------------------------------------------------------------
extern "C" void kernel_launch(void* const* d_in, const int* in_sizes, int n_in,
                              void* d_out, int out_size, void* d_ws, size_t ws_size,
                              hipStream_t stream)
{
    const float* x      = (const float*)d_in[0];
    const float* Win    = (const float*)d_in[1];
    const float* conv_w = (const float*)d_in[2];
    const float* conv_b = (const float*)d_in[3];
    const float* Wout   = (const float*)d_in[4];
    const float* Wm1    = (const float*)d_in[5];
    const float* bm1    = (const float*)d_in[6];
    const float* Wm2    = (const float*)d_in[7];
    const float* bm2    = (const float*)d_in[8];
    float* out = (float*)d_out;

    char* ws = (char*)d_ws;
    size_t o = 0;
    bf16*  xb    = (bf16*)(ws + o); o += (size_t)MTOK * CDIM * 2;
    bf16*  WinT  = (bf16*)(ws + o); o += (size_t)768 * 192 * 2;
    bf16*  WoutT = (bf16*)(ws + o); o += (size_t)192 * 384 * 2;
    bf16*  Wm1T  = (bf16*)(ws + o); o += (size_t)768 * 192 * 2;
    bf16*  Wm2T  = (bf16*)(ws + o); o += (size_t)192 * 768 * 2;
    float* wTc   = (float*)(ws + o); o += (size_t)9 * CIDIM * 4;
    bf16*  ws_x1 = (bf16*)(ws + o); o += (size_t)MTOK * CIDIM * 2;   // dense x1 [M,384]
    bf16*  ws_sz = (bf16*)(ws + o); o += (size_t)MTOK * CIDIM * 2;   // dense 4*silu(z)
    bf16*  ws_y  = (bf16*)(ws + o); o += (size_t)MTOK * CIDIM * 2;
    bf16*  ws_ob = (bf16*)(ws + o); o += (size_t)MTOK * CDIM * 2;    // out bf16 [M,192]
    bf16*  ws_h  = ws_x1;   // G4 output [M,768] reuses x1+sz region (dead by then)

    // 0) all conversions/transposes in one launch
    prep_all<<<dim3((SZ_ALL + 255) / 256), dim3(256), 0, stream>>>(
        x, Win, Wout, Wm1, Wm2, conv_w, xb, WinT, WoutT, Wm1T, Wm2T, wTc);

    // 1) xz = x @ Win  [M,768], K=192 -> split dense x1 / sz(=4*silu(z))
    //    persistent, TRUE async prefetch (counted vmcnt + raw barriers)
    gemm_k192_p<0><<<dim3(12 * NSTRIPE), dim3(256), 0, stream>>>(
        xb, WinT, nullptr, ws_x1, ws_sz);

    // 2) y = silu(dwconv(x1)+b) * sz -> bf16
    dwconv_gate_v6<<<dim3(MTOK * 48 / 256), dim3(256), 0, stream>>>(
        ws_x1, ws_sz, wTc, conv_b, ws_y);

    // 3) out = xb + y @ Wout   [M,192], K=384 -> bf16 ob (bf16 residual)
    gemm_mfma<1><<<dim3(3 * 256), dim3(256), 0, stream>>>(
        ws_y, WoutT, nullptr, xb, nullptr, ws_ob, MTOK, CDIM, CIDIM, 3);

    // 4) h = silu(out @ Wm1 + bm1)   [M,768], K=192 -> bf16 (persistent async)
    gemm_k192_p<2><<<dim3(12 * NSTRIPE), dim3(256), 0, stream>>>(
        ws_ob, Wm1T, bm1, ws_h, nullptr);

    // 5) final = bf16(out) + h @ Wm2 + bm2   [M,192], K=768 -> fp32
    gemm_mfma<3><<<dim3(3 * 256), dim3(256), 0, stream>>>(
        ws_h, Wm2T, bm2, ws_ob, out, nullptr, MTOK, CDIM, 768, 3);
}

// Round 16
// 117.133 us; speedup vs baseline: 1.8104x; 1.0466x over previous
//
#include <hip/hip_runtime.h>
#include <hip/hip_bf16.h>

// Problem constants
#define BDIM 8
#define HDIM 64
#define WDIM 64
#define CDIM 192
#define CIDIM 384
#define MTOK (BDIM * HDIM * WDIM)   // 32768 tokens

using bf16 = __hip_bfloat16;
typedef __attribute__((ext_vector_type(8))) short short8;   // 8 bf16 (4 VGPRs)
typedef __attribute__((ext_vector_type(4))) float f32x4;

__device__ __forceinline__ float silu_f(float v) { return v / (1.0f + __expf(-v)); }
__device__ __forceinline__ float bf2f(short s) {
    union { unsigned u; float f; } x; x.u = ((unsigned)(unsigned short)s) << 16; return x.f;
}

__device__ __forceinline__ void gload_lds16(const bf16* g, bf16* l) {
    __builtin_amdgcn_global_load_lds(
        (const __attribute__((address_space(1))) void*)g,
        (__attribute__((address_space(3))) void*)l, 16, 0, 0);
}

#define MFMA16(a, b, c) __builtin_amdgcn_mfma_f32_16x16x32_bf16(a, b, c, 0, 0, 0)

// ---------------------------------------------------------------------------
// PERSISTENT K=192 GEMM (G1) with counted-vmcnt async prefetch (R15 version).
// EPI 0: split c<384 -> outB (x1, stride 384); else outB2 = 4*silu(v)
// ---------------------------------------------------------------------------
#define NSTRIPE 40
template <int EPI>
__launch_bounds__(256, 2)
__global__ void gemm_k192_p(const bf16* __restrict__ A, const bf16* __restrict__ BT,
                            const float* __restrict__ bias,
                            bf16* __restrict__ outB, bf16* __restrict__ outB2)
{
    __shared__ bf16 As[2][64 * 192];
    __shared__ bf16 Bs[64 * 192];

    const int bid = blockIdx.x;
    const int n   = bid / NSTRIPE;
    const int s   = bid % NSTRIPE;
    const int n0  = n * 64;

    const int tid  = threadIdx.x;
    const int lane = tid & 63;
    const int wv   = tid >> 6;
    const int wm   = wv >> 1;
    const int wn   = wv & 1;

    int soff[6];
    #pragma unroll
    for (int i = 0; i < 6; ++i) {
        const int ci   = wv * 6 + i;
        const int c    = ci * 64 + lane;
        const int row  = c / 24;
        const int slot = c - row * 24;
        soff[i] = row * 192 + (slot ^ (row & 7)) * 8;
    }

    #pragma unroll
    for (int i = 0; i < 6; ++i)
        gload_lds16(BT + (size_t)n0 * 192 + soff[i], &Bs[(wv * 6 + i) * 512]);
    #pragma unroll
    for (int i = 0; i < 6; ++i)
        gload_lds16(A + (size_t)(s * 64) * 192 + soff[i], &As[0][(wv * 6 + i) * 512]);

    const int mloc[2] = { wm * 32 + (lane & 15), wm * 32 + 16 + (lane & 15) };
    const int nloc[2] = { wn * 32 + (lane & 15), wn * 32 + 16 + (lane & 15) };
    const bool isZ = (EPI == 0) && (n0 >= CIDIM);
    bf16* dst        = (EPI == 0) ? (isZ ? outB2 : outB) : outB;
    const int stride = (EPI == 0) ? CIDIM : 768;
    const int col0   = (EPI == 0) ? (isZ ? n0 - CIDIM : n0) : n0;

    int cur = 0;
    for (int mt = s; mt < 512; mt += NSTRIPE) {
        const int nmt = mt + NSTRIPE;
        if (nmt < 512) {
            const bf16* a1 = A + (size_t)(nmt * 64) * 192;
            bf16* db = As[cur ^ 1];
            #pragma unroll
            for (int i = 0; i < 6; ++i)
                gload_lds16(a1 + soff[i], &db[(wv * 6 + i) * 512]);
            asm volatile("s_waitcnt vmcnt(6)" ::: "memory");
        } else {
            asm volatile("s_waitcnt vmcnt(0)" ::: "memory");
        }
        __builtin_amdgcn_sched_barrier(0);
        __builtin_amdgcn_s_barrier();
        __builtin_amdgcn_sched_barrier(0);

        const bf16* la = As[cur];
        f32x4 acc[2][2] = {};
        __builtin_amdgcn_s_setprio(1);
        #pragma unroll
        for (int ks = 0; ks < 6; ++ks) {
            const int t = ks * 4 + (lane >> 4);
            short8 af[2], bfr[2];
            #pragma unroll
            for (int mi = 0; mi < 2; ++mi) {
                const int m = mloc[mi];
                af[mi] = *reinterpret_cast<const short8*>(&la[m * 192 + ((t ^ (m & 7)) << 3)]);
            }
            #pragma unroll
            for (int ni = 0; ni < 2; ++ni) {
                const int nn = nloc[ni];
                bfr[ni] = *reinterpret_cast<const short8*>(&Bs[nn * 192 + ((t ^ (nn & 7)) << 3)]);
            }
            #pragma unroll
            for (int mi = 0; mi < 2; ++mi)
                #pragma unroll
                for (int ni = 0; ni < 2; ++ni)
                    acc[mi][ni] = MFMA16(af[mi], bfr[ni], acc[mi][ni]);
        }
        __builtin_amdgcn_s_setprio(0);

        __builtin_amdgcn_sched_barrier(0);
        __builtin_amdgcn_s_barrier();
        __builtin_amdgcn_sched_barrier(0);

        const int m0   = mt * 64;
        const int rowb = m0 + wm * 32 + (lane >> 4) * 4;
        const int colb = col0 + wn * 32 + (lane & 15);
        #pragma unroll
        for (int mi = 0; mi < 2; ++mi) {
            #pragma unroll
            for (int ni = 0; ni < 2; ++ni) {
                const int c = colb + ni * 16;
                #pragma unroll
                for (int j = 0; j < 4; ++j) {
                    const int row = rowb + mi * 16 + j;
                    float v = acc[mi][ni][j];
                    if constexpr (EPI == 0) {
                        if (isZ) v = 4.0f * silu_f(v);
                    } else {
                        v = silu_f(v + bias[n0 + (c - col0)]);
                    }
                    dst[(size_t)row * stride + c] = __float2bfloat16(v);
                }
            }
        }
        cur ^= 1;
    }
}

// ---------------------------------------------------------------------------
// G3 loop GEMM (K=384): out = bf16(xb + y@Wout). BM=128, BN=64, BK=64.
// ---------------------------------------------------------------------------
__launch_bounds__(256, 4)
__global__ void gemm_g3(const bf16* __restrict__ A, const bf16* __restrict__ BT,
                        const bf16* __restrict__ residB, bf16* __restrict__ outB,
                        int M, int N, int K, int NX)
{
    __shared__ bf16 As[128 * 64];
    __shared__ bf16 Bs[64 * 64];

    const int bid = blockIdx.x;
    const int c8  = bid & 7;
    const int kq  = bid >> 3;
    const int bx  = kq % NX;
    const int by  = (kq / NX) * 8 + c8;
    const int m0  = by * 128;
    const int n0  = bx * 64;

    const int tid  = threadIdx.x;
    const int lane = tid & 63;
    const int wv   = tid >> 6;
    const int wm   = wv >> 1;
    const int wn   = wv & 1;

    const int srow  = lane >> 3;
    const int sslot = lane & 7;

    f32x4 acc[4][2] = {};

    for (int k0 = 0; k0 < K; k0 += 64) {
        #pragma unroll
        for (int i = 0; i < 4; ++i) {
            const int rb = wv * 32 + i * 8;
            const int r  = rb + srow;
            gload_lds16(A + (size_t)(m0 + r) * K + k0 + ((sslot ^ (r & 7)) << 3),
                        &As[rb * 64]);
        }
        #pragma unroll
        for (int i = 0; i < 2; ++i) {
            const int rb = wv * 16 + i * 8;
            const int r  = rb + srow;
            gload_lds16(BT + (size_t)(n0 + r) * K + k0 + ((sslot ^ (r & 7)) << 3),
                        &Bs[rb * 64]);
        }
        __syncthreads();

        #pragma unroll
        for (int kk = 0; kk < 2; ++kk) {
            const int t = kk * 4 + (lane >> 4);
            short8 af[4], bfr[2];
            #pragma unroll
            for (int mi = 0; mi < 4; ++mi) {
                const int m = wm * 64 + mi * 16 + (lane & 15);
                af[mi] = *reinterpret_cast<const short8*>(&As[m * 64 + ((t ^ (m & 7)) << 3)]);
            }
            #pragma unroll
            for (int ni = 0; ni < 2; ++ni) {
                const int n = wn * 32 + ni * 16 + (lane & 15);
                bfr[ni] = *reinterpret_cast<const short8*>(&Bs[n * 64 + ((t ^ (n & 7)) << 3)]);
            }
            #pragma unroll
            for (int mi = 0; mi < 4; ++mi)
                #pragma unroll
                for (int ni = 0; ni < 2; ++ni)
                    acc[mi][ni] = MFMA16(af[mi], bfr[ni], acc[mi][ni]);
        }
        __syncthreads();
    }

    const int colb = n0 + wn * 32 + (lane & 15);
    const int rowb = m0 + wm * 64 + (lane >> 4) * 4;
    #pragma unroll
    for (int mi = 0; mi < 4; ++mi) {
        #pragma unroll
        for (int ni = 0; ni < 2; ++ni) {
            const int c = colb + ni * 16;
            #pragma unroll
            for (int j = 0; j < 4; ++j) {
                const int row = rowb + mi * 16 + j;
                const size_t off = (size_t)row * N + c;
                outB[off] = __float2bfloat16(acc[mi][ni][j] +
                                             bf2f(*(const short*)&residB[off]));
            }
        }
    }
}

// ---------------------------------------------------------------------------
// FUSED MLP (G4+G5), 32-row tiles: final = ob + silu(ob@Wm1+bm1)@Wm2 + bm2.
// LDS: obs 12KB + hs 32x776 (48.5KB) = 60.5KB -> 2 blocks/CU (8 waves/CU).
// Weights pre-laid FRAGMENT-ORDER (Wm1F 48frag x 6ks, Wm2F 12frag x 24ks):
// each B-frag load = contiguous 1KB wave-line from L2 (global_load_dwordx4).
// hs stride 776 elems -> all LDS traffic <=2-way (free). No h round-trip.
// ---------------------------------------------------------------------------
#define HSTR 776
__launch_bounds__(256, 2)
__global__ void fused_mlp32(const bf16* __restrict__ ob, const bf16* __restrict__ Wm1F,
                            const bf16* __restrict__ Wm2F, const float* __restrict__ bm1,
                            const float* __restrict__ bm2, float* __restrict__ out)
{
    __shared__ bf16 obs[32 * 192];     // 12 KB
    __shared__ bf16 hs[32 * HSTR];     // 48.5 KB

    const int m0   = blockIdx.x * 32;
    const int tid  = threadIdx.x;
    const int lane = tid & 63;
    const int wv   = tid >> 6;
    const int l15  = lane & 15;
    const int l4   = lane >> 4;

    // stage obs (768 16B chunks; k192 slot swizzle p^(row&7))
    #pragma unroll
    for (int i = 0; i < 3; ++i) {
        const int ci   = wv * 3 + i;
        const int c    = ci * 64 + lane;
        const int row  = c / 24;
        const int slot = c - row * 24;
        gload_lds16(ob + (size_t)(m0 + row) * 192 + ((slot ^ (row & 7)) << 3),
                    &obs[ci * 512]);
    }
    __syncthreads();

    // ---- phase 1: h[32x768] per wave 192 cols, 3 groups of 4 n-frags ----
    #pragma unroll
    for (int g = 0; g < 3; ++g) {
        f32x4 hacc[2][4] = {};
        #pragma unroll
        for (int ks = 0; ks < 6; ++ks) {
            short8 af[2];
            #pragma unroll
            for (int mi = 0; mi < 2; ++mi) {
                const int r = mi * 16 + l15;
                af[mi] = *reinterpret_cast<const short8*>(
                    &obs[r * 192 + (((ks * 4 + l4) ^ (r & 7)) << 3)]);
            }
            #pragma unroll
            for (int ni = 0; ni < 4; ++ni) {
                const int f = wv * 12 + g * 4 + ni;     // global n-frag 0..47
                const short8 b = *reinterpret_cast<const short8*>(
                    Wm1F + ((size_t)(f * 6 + ks) * 64 + lane) * 8);
                #pragma unroll
                for (int mi = 0; mi < 2; ++mi)
                    hacc[mi][ni] = MFMA16(af[mi], b, hacc[mi][ni]);
            }
        }
        #pragma unroll
        for (int ni = 0; ni < 4; ++ni) {
            const int col = (wv * 12 + g * 4 + ni) * 16 + l15;
            const float bb = bm1[col];
            #pragma unroll
            for (int mi = 0; mi < 2; ++mi)
                #pragma unroll
                for (int j = 0; j < 4; ++j) {
                    const int r = mi * 16 + l4 * 4 + j;
                    hs[r * HSTR + col] = __float2bfloat16(silu_f(hacc[mi][ni][j] + bb));
                }
        }
    }
    __syncthreads();

    // ---- phase 2: out[32x192], K=768; wave owns 48 cols ----
    f32x4 facc[2][3] = {};
    for (int ks = 0; ks < 24; ++ks) {
        short8 ha[2];
        #pragma unroll
        for (int mi = 0; mi < 2; ++mi) {
            const int r = mi * 16 + l15;
            ha[mi] = *reinterpret_cast<const short8*>(&hs[r * HSTR + ks * 32 + l4 * 8]);
        }
        #pragma unroll
        for (int ni = 0; ni < 3; ++ni) {
            const int f = wv * 3 + ni;                  // out n-frag 0..11
            const short8 b = *reinterpret_cast<const short8*>(
                Wm2F + ((size_t)(f * 24 + ks) * 64 + lane) * 8);
            #pragma unroll
            for (int mi = 0; mi < 2; ++mi)
                facc[mi][ni] = MFMA16(ha[mi], b, facc[mi][ni]);
        }
    }

    // epilogue: + bm2 + bf16 ob residual (from obs), fp32 out
    #pragma unroll
    for (int ni = 0; ni < 3; ++ni) {
        const int col = (wv * 3 + ni) * 16 + l15;
        const float b2 = bm2[col];
        #pragma unroll
        for (int mi = 0; mi < 2; ++mi)
            #pragma unroll
            for (int j = 0; j < 4; ++j) {
                const int r  = mi * 16 + l4 * 4 + j;
                const int ch = (col >> 3) ^ (r & 7);
                const float resid = bf2f(*reinterpret_cast<const short*>(
                    &obs[r * 192 + ch * 8 + (col & 7)]));
                out[(size_t)(m0 + r) * 192 + col] = facc[mi][ni][j] + b2 + resid;
            }
    }
}

// ---------------------------------------------------------------------------
// Depthwise 3x3 conv + bias + silu, gated (dense streams).
// ---------------------------------------------------------------------------
__launch_bounds__(256)
__global__ void dwconv_gate_v6(const bf16* __restrict__ x1, const bf16* __restrict__ sz,
                               const float* __restrict__ wT, const float* __restrict__ conv_b,
                               bf16* __restrict__ y)
{
    const int bid = blockIdx.x;
    const int swz = (bid & 7) * ((int)gridDim.x >> 3) + (bid >> 3);
    const int f   = swz * 256 + threadIdx.x;
    const int m   = f / 48;
    const int cg  = f - m * 48;
    const int c0  = cg * 8;
    const int h   = (m >> 6) & 63;
    const int w   = m & 63;

    float acc[8];
    {
        const f32x4 ba = *reinterpret_cast<const f32x4*>(&conv_b[c0]);
        const f32x4 bb = *reinterpret_cast<const f32x4*>(&conv_b[c0 + 4]);
        acc[0] = ba[0]; acc[1] = ba[1]; acc[2] = ba[2]; acc[3] = ba[3];
        acc[4] = bb[0]; acc[5] = bb[1]; acc[6] = bb[2]; acc[7] = bb[3];
    }

    #pragma unroll
    for (int r = 0; r < 3; ++r) {
        const int hh = h + r - 1;
        if (hh < 0 || hh >= HDIM) continue;
        #pragma unroll
        for (int dw = 0; dw < 3; ++dw) {
            const int ww = w + dw - 1;
            if (ww < 0 || ww >= WDIM) continue;
            const int mm  = m + (r - 1) * WDIM + (dw - 1);
            const int tap = r * 3 + dw;
            const short8 t = *reinterpret_cast<const short8*>(&x1[(size_t)mm * CIDIM + c0]);
            const f32x4 wa = *reinterpret_cast<const f32x4*>(&wT[tap * CIDIM + c0]);
            const f32x4 wb = *reinterpret_cast<const f32x4*>(&wT[tap * CIDIM + c0 + 4]);
            acc[0] += bf2f(t[0]) * wa[0]; acc[1] += bf2f(t[1]) * wa[1];
            acc[2] += bf2f(t[2]) * wa[2]; acc[3] += bf2f(t[3]) * wa[3];
            acc[4] += bf2f(t[4]) * wb[0]; acc[5] += bf2f(t[5]) * wb[1];
            acc[6] += bf2f(t[6]) * wb[2]; acc[7] += bf2f(t[7]) * wb[3];
        }
    }

    const short8 g = *reinterpret_cast<const short8*>(&sz[(size_t)m * CIDIM + c0]);
    bf16 tmp[8];
    #pragma unroll
    for (int j = 0; j < 8; ++j)
        tmp[j] = __float2bfloat16(silu_f(acc[j]) * bf2f(g[j]));
    *reinterpret_cast<short8*>(&y[(size_t)m * CIDIM + c0]) =
        *reinterpret_cast<const short8*>(tmp);
}

// ---------------------------------------------------------------------------
// ALL preprocessing in ONE launch: x->bf16, WinT/WoutT transposes,
// Wm1F/Wm2F FRAGMENT-ORDER layouts, conv_w transpose.
// ---------------------------------------------------------------------------
#define SZ_WIN  (192 * 768)
#define SZ_WOUT (384 * 192)
#define SZ_WM1  (192 * 768)
#define SZ_WM2  (768 * 192)
#define SZ_CW   (CIDIM * 9)
#define XCVT    (MTOK * CDIM / 4)
#define SZ_ALL  (XCVT + SZ_WIN + SZ_WOUT + SZ_WM1 + SZ_WM2 + SZ_CW)

__launch_bounds__(256)
__global__ void prep_all(const float* __restrict__ x, const float* __restrict__ Win,
                         const float* __restrict__ Wout, const float* __restrict__ Wm1,
                         const float* __restrict__ Wm2, const float* __restrict__ convw,
                         bf16* __restrict__ xb, bf16* __restrict__ WinT,
                         bf16* __restrict__ WoutT, bf16* __restrict__ Wm1F,
                         bf16* __restrict__ Wm2F, float* __restrict__ wTc)
{
    int idx = blockIdx.x * 256 + threadIdx.x;
    if (idx < XCVT) {
        const int i = idx * 4;
        const float4 v = *reinterpret_cast<const float4*>(&x[i]);
        xb[i + 0] = __float2bfloat16(v.x);
        xb[i + 1] = __float2bfloat16(v.y);
        xb[i + 2] = __float2bfloat16(v.z);
        xb[i + 3] = __float2bfloat16(v.w);
        return;
    }
    idx -= XCVT;
    if (idx < SZ_WIN) {
        const int r = idx / 768, c = idx % 768;
        WinT[(size_t)c * 192 + r] = __float2bfloat16(Win[idx]);
        return;
    }
    idx -= SZ_WIN;
    if (idx < SZ_WOUT) {
        const int r = idx / 192, c = idx % 192;
        WoutT[(size_t)c * 384 + r] = __float2bfloat16(Wout[idx]);
        return;
    }
    idx -= SZ_WOUT;
    if (idx < SZ_WM1) {
        // fragment order: [f:48][ks:6][lane:64][e:8]; row=f*16+(l&15), k=ks*32+(l>>4)*8+e
        const int f  = idx / 3072;
        const int r1 = idx - f * 3072;
        const int ks = r1 / 512;
        const int r2 = r1 - ks * 512;
        const int l  = r2 >> 3;
        const int e  = r2 & 7;
        const int row = f * 16 + (l & 15);
        const int k   = ks * 32 + (l >> 4) * 8 + e;
        Wm1F[idx] = __float2bfloat16(Wm1[(size_t)k * 768 + row]);
        return;
    }
    idx -= SZ_WM1;
    if (idx < SZ_WM2) {
        // fragment order: [f:12][ks:24][lane:64][e:8]; row=f*16+(l&15), k=ks*32+(l>>4)*8+e
        const int f  = idx / 12288;
        const int r1 = idx - f * 12288;
        const int ks = r1 / 512;
        const int r2 = r1 - ks * 512;
        const int l  = r2 >> 3;
        const int e  = r2 & 7;
        const int row = f * 16 + (l & 15);
        const int k   = ks * 32 + (l >> 4) * 8 + e;
        Wm2F[idx] = __float2bfloat16(Wm2[(size_t)k * 192 + row]);
        return;
    }
    idx -= SZ_WM2;
    if (idx < SZ_CW) {
        const int ci = idx / 9, t = idx % 9;
        wTc[t * CIDIM + ci] = convw[idx];
    }
}

// ---------------------------------------------------------------------------
extern "C" void kernel_launch(void* const* d_in, const int* in_sizes, int n_in,
                              void* d_out, int out_size, void* d_ws, size_t ws_size,
                              hipStream_t stream)
{
    const float* x      = (const float*)d_in[0];
    const float* Win    = (const float*)d_in[1];
    const float* conv_w = (const float*)d_in[2];
    const float* conv_b = (const float*)d_in[3];
    const float* Wout   = (const float*)d_in[4];
    const float* Wm1    = (const float*)d_in[5];
    const float* bm1    = (const float*)d_in[6];
    const float* Wm2    = (const float*)d_in[7];
    const float* bm2    = (const float*)d_in[8];
    float* out = (float*)d_out;

    char* ws = (char*)d_ws;
    size_t o = 0;
    bf16*  xb    = (bf16*)(ws + o); o += (size_t)MTOK * CDIM * 2;
    bf16*  WinT  = (bf16*)(ws + o); o += (size_t)768 * 192 * 2;
    bf16*  WoutT = (bf16*)(ws + o); o += (size_t)192 * 384 * 2;
    bf16*  Wm1F  = (bf16*)(ws + o); o += (size_t)SZ_WM1 * 2;
    bf16*  Wm2F  = (bf16*)(ws + o); o += (size_t)SZ_WM2 * 2;
    float* wTc   = (float*)(ws + o); o += (size_t)9 * CIDIM * 4;
    bf16*  ws_x1 = (bf16*)(ws + o); o += (size_t)MTOK * CIDIM * 2;   // dense x1 [M,384]
    bf16*  ws_sz = (bf16*)(ws + o); o += (size_t)MTOK * CIDIM * 2;   // dense 4*silu(z)
    bf16*  ws_y  = (bf16*)(ws + o); o += (size_t)MTOK * CIDIM * 2;
    bf16*  ws_ob = (bf16*)(ws + o); o += (size_t)MTOK * CDIM * 2;    // out bf16 [M,192]

    // 0) all conversions / re-layouts in one launch
    prep_all<<<dim3((SZ_ALL + 255) / 256), dim3(256), 0, stream>>>(
        x, Win, Wout, Wm1, Wm2, conv_w, xb, WinT, WoutT, Wm1F, Wm2F, wTc);

    // 1) xz = x @ Win  [M,768], K=192 -> split dense x1 / sz(=4*silu(z))
    gemm_k192_p<0><<<dim3(12 * NSTRIPE), dim3(256), 0, stream>>>(
        xb, WinT, nullptr, ws_x1, ws_sz);

    // 2) y = silu(dwconv(x1)+b) * sz -> bf16
    dwconv_gate_v6<<<dim3(MTOK * 48 / 256), dim3(256), 0, stream>>>(
        ws_x1, ws_sz, wTc, conv_b, ws_y);

    // 3) out = xb + y @ Wout   [M,192], K=384 -> bf16 ob
    gemm_g3<<<dim3(3 * 256), dim3(256), 0, stream>>>(
        ws_y, WoutT, xb, ws_ob, MTOK, CDIM, CIDIM, 3);

    // 4+5) final = ob + silu(ob@Wm1+bm1)@Wm2 + bm2 -> fp32 out (FUSED, 32-row)
    fused_mlp32<<<dim3(MTOK / 32), dim3(256), 0, stream>>>(
        ws_ob, Wm1F, Wm2F, bm1, bm2, out);
}